// Round 6
// baseline (658.721 us; speedup 1.0000x reference)
//
#include <hip/hip_runtime.h>
#include <cmath>
#include <cstdint>
#include <cstddef>

typedef unsigned long long u64;
typedef unsigned int u32;

#define NPX   2500
#define NANCH 22500
#define PRE_TOPK 10000
#define NWORDS 160      // 160*64 = 10240 bits per NMS row

struct AnchorBase { float b[36]; };
struct Box8 { float x1, y1, x2, y2, a, p0, p1, p2; };

typedef __attribute__((ext_vector_type(8))) short bf16x8;
typedef __attribute__((ext_vector_type(4))) float f32x4;

__device__ inline unsigned short f2bf(float f) {
    u32 u = __float_as_uint(f);
    u32 r = u + 0x7fffu + ((u >> 16) & 1u);
    return (unsigned short)(r >> 16);
}
__device__ inline float bf2f(unsigned short h) {
    return __uint_as_float(((u32)h) << 16);
}

// ---------------------------------------------------------------------------
// KPREP: fused input prep (Xt bf16 hi/lo padded grid; W' bf16 hi/lo).
// ---------------------------------------------------------------------------
__global__ __launch_bounds__(256) void kprep(const float* __restrict__ feat,
                                             const float* __restrict__ wr,
                                             unsigned short* __restrict__ xthi,
                                             unsigned short* __restrict__ xtlo,
                                             unsigned short* __restrict__ whi,
                                             unsigned short* __restrict__ wlo)
{
    __shared__ float sh[4608];
    int bid = blockIdx.x;
    int t = threadIdx.x;
    if (bid < 416) {
        float (*tile)[65] = (float(*)[65])sh;
        int gr = bid >> 3;          // grid row 0..51
        int cc = bid & 7;           // c-chunk
        int tx = t & 63, ty = t >> 6;
        int y = gr - 1;
        bool rowok = (gr >= 1) && (gr <= 50);
#pragma unroll
        for (int i = 0; i < 16; ++i) {
            int c = i * 4 + ty;
            tile[c][tx] = (rowok && tx < 50)
                        ? feat[(size_t)(cc * 64 + c) * NPX + y * 50 + tx] : 0.f;
        }
        __syncthreads();
#pragma unroll
        for (int i = 0; i < 16; ++i) {
            int xp = i * 4 + ty;
            int cell = gr * 64 + xp;
            bool ok = rowok && xp >= 1 && xp <= 50;
            float v = ok ? tile[tx][xp - 1] : 0.f;
            unsigned short hi = f2bf(v);
            xthi[(size_t)cell * 512 + cc * 64 + tx] = hi;
            xtlo[(size_t)cell * 512 + cc * 64 + tx] = f2bf(v - bf2f(hi));
        }
    } else {
        int oc = bid - 416;         // 0..511
        for (int j = t; j < 4608; j += 256) sh[j] = wr[(size_t)oc * 4608 + j];
        __syncthreads();
        for (int k = t; k < 4608; k += 256) {
            int c = k & 511, tap = k >> 9;
            float v = sh[c * 9 + tap];
            unsigned short hi = f2bf(v);
            whi[(size_t)oc * 4608 + k] = hi;
            wlo[(size_t)oc * 4608 + k] = f2bf(v - bf2f(hi));
        }
    }
}

// ---------------------------------------------------------------------------
// K1m v4: conv as bf16x3 MFMA GEMM. Wave = 32oc x 32px; block = 64oc x 64px.
// Grid (40, 8, ns) = 1280*ns/4 blocks -> 5120 waves at ns=4 (62% occupancy;
// R5's 2560 waves capped occupancy at 28% and MfmaUtil at 11%).
// ---------------------------------------------------------------------------
struct Frag { bf16x8 ah0, ah1, al0, al1, bh0, bh1, bl0, bl1; };

__device__ inline void k1_load(Frag& F, int it, int cperm1, int cperLog, int chb,
                               int quad, int p0, int p1,
                               size_t wrow0, size_t wrow1,
                               const unsigned short* __restrict__ xthi,
                               const unsigned short* __restrict__ xtlo,
                               const unsigned short* __restrict__ whi,
                               const unsigned short* __restrict__ wlo)
{
    int tap = it >> cperLog;
    int cw  = it & cperm1;
    int kq  = (chb + cw) * 32 + quad * 8;
    int kw  = tap * 512 + kq;
    int t3  = (tap * 43) >> 7;             // tap/3
    int tapoff = (t3 - 1) * 64 + (tap - t3 * 3) - 1;
    F.ah0 = *(const bf16x8*)(whi + wrow0 + kw);
    F.ah1 = *(const bf16x8*)(whi + wrow1 + kw);
    F.al0 = *(const bf16x8*)(wlo + wrow0 + kw);
    F.al1 = *(const bf16x8*)(wlo + wrow1 + kw);
    size_t o0 = (size_t)(p0 + tapoff) * 512 + kq;
    size_t o1 = (size_t)(p1 + tapoff) * 512 + kq;
    F.bh0 = *(const bf16x8*)(xthi + o0);
    F.bh1 = *(const bf16x8*)(xthi + o1);
    F.bl0 = *(const bf16x8*)(xtlo + o0);
    F.bl1 = *(const bf16x8*)(xtlo + o1);
}

__device__ inline void k1_step(const Frag& F, f32x4* a)
{
#define MF(d, A, B) d = __builtin_amdgcn_mfma_f32_16x16x32_bf16(F.A, F.B, d, 0, 0, 0)
    MF(a[0], al0, bh0); MF(a[0], ah0, bl0); MF(a[0], ah0, bh0);
    MF(a[1], al0, bh1); MF(a[1], ah0, bl1); MF(a[1], ah0, bh1);
    MF(a[2], al1, bh0); MF(a[2], ah1, bl0); MF(a[2], ah1, bh0);
    MF(a[3], al1, bh1); MF(a[3], ah1, bl1); MF(a[3], ah1, bh1);
#undef MF
}

__global__ __launch_bounds__(256) void k1m(const unsigned short* __restrict__ xthi,
                                           const unsigned short* __restrict__ xtlo,
                                           const unsigned short* __restrict__ whi,
                                           const unsigned short* __restrict__ wlo,
                                           float* __restrict__ pk,
                                           int cper, int cperLog)
{
    int t = threadIdx.x;
    int lane = t & 63, wave = t >> 6;
    int wo = wave & 1, wp = wave >> 1;
    int pb = blockIdx.x, ob = blockIdx.y, bs = blockIdx.z;
    int quad = lane >> 4, m = lane & 15;
    int ocbase = ob * 64 + wo * 32;
    int pxbase = pb * 64 + wp * 32;
    int chb = bs * cper;
    int cperm1 = cper - 1;

    int prow[2];
#pragma unroll
    for (int sp = 0; sp < 2; ++sp) {
        int opx = pxbase + sp * 16 + m;
        prow[sp] = (opx < NPX) ? ((opx / 50) + 1) * 64 + (opx % 50) + 1 : 190;
    }
    size_t wrow0 = (size_t)(ocbase + m) * 4608;
    size_t wrow1 = wrow0 + (size_t)16 * 4608;

    f32x4 acc[4];
    f32x4 zf = {0.f, 0.f, 0.f, 0.f};
#pragma unroll
    for (int i = 0; i < 4; ++i) acc[i] = zf;

    int niter = 9 * cper;   // 18 / 36 / 72, always even
    Frag F0, F1;
    k1_load(F0, 0, cperm1, cperLog, chb, quad, prow[0], prow[1],
            wrow0, wrow1, xthi, xtlo, whi, wlo);
    for (int it = 0; it < niter; it += 2) {
        k1_load(F1, it + 1, cperm1, cperLog, chb, quad, prow[0], prow[1],
                wrow0, wrow1, xthi, xtlo, whi, wlo);
        k1_step(F0, acc);
        if (it + 2 < niter)
            k1_load(F0, it + 2, cperm1, cperLog, chb, quad, prow[0], prow[1],
                    wrow0, wrow1, xthi, xtlo, whi, wlo);
        k1_step(F1, acc);
    }
    // C/D: col(px)=lane&15, row(oc)=quad*4+reg
#pragma unroll
    for (int so = 0; so < 2; ++so)
#pragma unroll
        for (int sp = 0; sp < 2; ++sp)
#pragma unroll
            for (int r = 0; r < 4; ++r) {
                int oc = ocbase + so * 16 + quad * 4 + r;
                int px = pxbase + sp * 16 + m;
                pk[((size_t)bs * 512 + oc) * 2560 + px] = acc[so * 2 + sp][r];
            }
}

// ---------------------------------------------------------------------------
// K2a: fused k-split reduce + bias + ReLU + 1x1 heads partial GEMM.
// Grid (40 px-tiles, 8 c-chunks) = 320 blocks.
// ---------------------------------------------------------------------------
__global__ __launch_bounds__(256) void k2a_heads(const float* __restrict__ pk, int ns,
                                                 const float* __restrict__ br,
                                                 const float* __restrict__ wcls,
                                                 const float* __restrict__ wreg,
                                                 float* __restrict__ part)
{
    __shared__ float vt[64 * 64];
    __shared__ float Wl[45 * 64];
    int t  = threadIdx.x;
    int pb = blockIdx.x;           // 0..39
    int s  = blockIdx.y;           // 0..7
    int cb = s * 64;
    for (int e = t; e < 45 * 64; e += 256) {
        int u = e >> 6, c = e & 63;
        Wl[e] = (u < 9) ? wcls[u * 512 + cb + c] : wreg[(u - 9) * 512 + cb + c];
    }
    int pxl = t & 63, ug = t >> 6;
    int px = pb * 64 + pxl;
    bool ok = px < NPX;
#pragma unroll
    for (int i = 0; i < 16; ++i) {
        int c = ug * 16 + i;       // wave-uniform
        float v = 0.f;
        if (ok) {
            size_t bidx = (size_t)(cb + c) * 2560 + px;
            v = br[cb + c];
            for (int ks = 0; ks < ns; ++ks) v += pk[(size_t)ks * 512 * 2560 + bidx];
            v = v > 0.f ? v : 0.f;
        }
        vt[c * 64 + pxl] = v;
    }
    __syncthreads();
    int ubase = ug * 12;
    int ulim  = (45 - ubase < 12) ? (45 - ubase) : 12;
    float acc[12];
#pragma unroll
    for (int j = 0; j < 12; ++j) acc[j] = 0.f;
    for (int c = 0; c < 64; ++c) {
        float v = vt[c * 64 + pxl];
#pragma unroll
        for (int j = 0; j < 12; ++j)
            acc[j] = fmaf(v, Wl[(ubase + j) * 64 + c], acc[j]);
    }
    if (ok) {
        for (int j = 0; j < ulim; ++j)
            part[((size_t)s * 45 + ubase + j) * NPX + px] = acc[j];
    }
}

// ---------------------------------------------------------------------------
// K2b: reduce partials + bias, sigmoid, decode, clip, validity, sort key.
// ---------------------------------------------------------------------------
__global__ __launch_bounds__(256) void k2b_decode(const float* __restrict__ part,
                                                  const float* __restrict__ bcls,
                                                  const float* __restrict__ breg,
                                                  AnchorBase ab,
                                                  float* __restrict__ score,
                                                  float* __restrict__ bx1, float* __restrict__ by1,
                                                  float* __restrict__ bx2, float* __restrict__ by2,
                                                  u32* __restrict__ valid,
                                                  u64* __restrict__ key)
{
    int id = blockIdx.x * 256 + threadIdx.x;
    if (id >= NANCH) return;
    int k  = id / NPX;
    int px = id - k * NPX;

    float z  = bcls[k];
    float d0 = breg[k * 4 + 0], d1 = breg[k * 4 + 1];
    float d2 = breg[k * 4 + 2], d3 = breg[k * 4 + 3];
#pragma unroll
    for (int s = 0; s < 8; ++s) {
        const float* p = part + (size_t)s * 45 * NPX;
        z  += p[(size_t)k * NPX + px];
        d0 += p[(size_t)(9 + k * 4 + 0) * NPX + px];
        d1 += p[(size_t)(9 + k * 4 + 1) * NPX + px];
        d2 += p[(size_t)(9 + k * 4 + 2) * NPX + px];
        d3 += p[(size_t)(9 + k * 4 + 3) * NPX + px];
    }
    float sc = 1.f / (1.f + expf(-z));

    int yy = px / 50, xx = px - (px / 50) * 50;
    float fx = (float)xx, fy = (float)yy;
    float ax1 = fx + ab.b[k * 4 + 0], ay1 = fy + ab.b[k * 4 + 1];
    float ax2 = fx + ab.b[k * 4 + 2], ay2 = fy + ab.b[k * 4 + 3];
    float aw = ax2 - ax1, ah = ay2 - ay1;
    float cx = ax1 + 0.5f * aw, cy = ay1 + 0.5f * ah;
    float pcx = d0 * aw + cx, pcy = d1 * ah + cy;
    float pw = expf(d2) * aw, ph = expf(d3) * ah;
    float x1 = pcx - 0.5f * pw, y1 = pcy - 0.5f * ph;
    float x2 = pcx + 0.5f * pw, y2 = pcy + 0.5f * ph;
    x1 = fminf(fmaxf(x1, 0.f), 800.f);
    y1 = fminf(fmaxf(y1, 0.f), 800.f);
    x2 = fminf(fmaxf(x2, 0.f), 800.f);
    y2 = fminf(fmaxf(y2, 0.f), 800.f);
    u32 v = ((x2 - x1) >= 16.f) && ((y2 - y1) >= 16.f);

    int f = px * 9 + k;
    score[f] = sc;
    bx1[f] = x1; by1[f] = y1; bx2[f] = x2; by2[f] = y2;
    valid[f] = v;
    u32 sb = __float_as_uint(sc);
    key[f] = ((u64)(~sb) << 32) | (u32)f;
}

// ---------------------------------------------------------------------------
// K3a v2: partial ranks via SGPR-resident keys (no LDS — the R5 version's
// 4500 ds_read broadcasts per wave were DS-pipe-bound ~50 us). j-keys are
// wave-uniform -> scalar loads; compare is v_cmp with SGPR operand.
// Grid (88, 9): j-chunks of 2500.
// ---------------------------------------------------------------------------
__global__ __launch_bounds__(256) void k3a_rank(const u64* __restrict__ key,
                                                u32* __restrict__ rankp)
{
    int i = blockIdx.x * 256 + threadIdx.x;
    if (i >= NANCH) return;
    u64 ki = key[i];
    const u64* kp = key + blockIdx.y * 2500;
    u32 cnt = 0;
#pragma unroll 10
    for (int j = 0; j < 2500; ++j)
        cnt += (kp[j] < ki) ? 1u : 0u;
    rankp[(size_t)blockIdx.y * NANCH + i] = cnt;
}

// ---------------------------------------------------------------------------
// K3b: sum 9 partial ranks, scatter top-10000 (+ packed Box8 for k4's scalar
// j-loads); sInv[r] = 1 if invalid box.
// ---------------------------------------------------------------------------
__global__ __launch_bounds__(256) void k3b_gather(const u32* __restrict__ rankp,
                                                  const float* __restrict__ score,
                                                  const float* __restrict__ bx1, const float* __restrict__ by1,
                                                  const float* __restrict__ bx2, const float* __restrict__ by2,
                                                  const u32* __restrict__ valid,
                                                  float* __restrict__ sS,
                                                  float* __restrict__ sx1, float* __restrict__ sy1,
                                                  float* __restrict__ sx2, float* __restrict__ sy2,
                                                  Box8* __restrict__ sbox,
                                                  u32* __restrict__ sInv)
{
    int i = blockIdx.x * 256 + threadIdx.x;
    if (i >= NANCH) return;
    u32 r = 0;
#pragma unroll
    for (int c = 0; c < 9; ++c) r += rankp[(size_t)c * NANCH + i];
    if (r >= PRE_TOPK) return;
    float x1 = bx1[i], y1 = by1[i], x2 = bx2[i], y2 = by2[i];
    sS[r] = score[i];
    sx1[r] = x1; sy1[r] = y1; sx2[r] = x2; sy2[r] = y2;
    Box8 b;
    b.x1 = x1; b.y1 = y1; b.x2 = x2; b.y2 = y2;
    b.a = (x2 - x1) * (y2 - y1);
    b.p0 = 0.f; b.p1 = 0.f; b.p2 = 0.f;
    sbox[r] = b;
    sInv[r] = valid[i] ? 0u : 1u;
}

// ---------------------------------------------------------------------------
// K4 v2: suppression matrix with j-boxes via scalar loads (no LDS — R5's 5120
// ds broadcasts per wave were DS-pipe-bound ~50 us). selfw[i] = rows[i][i>>6].
// ---------------------------------------------------------------------------
__global__ __launch_bounds__(256) void k4_mat(const float* __restrict__ sx1, const float* __restrict__ sy1,
                                              const float* __restrict__ sx2, const float* __restrict__ sy2,
                                              const Box8* __restrict__ sbox,
                                              u64* __restrict__ rows,
                                              u64* __restrict__ selfw)
{
    int t  = threadIdx.x;
    int ib = blockIdx.x;           // 0..39
    int jc = blockIdx.y;           // 0..9
    int i = ib * 256 + t;
    if (i >= PRE_TOPK) return;
    u64* rowp = rows + (size_t)i * NWORDS + jc * 16;
    if (jc * 1024 + 1023 <= i) {   // whole chunk has j <= i -> zeros
#pragma unroll
        for (int w = 0; w < 16; ++w) rowp[w] = 0ull;
        int sw_ = i >> 6;
        if (sw_ >= jc * 16 && sw_ < jc * 16 + 16) selfw[i] = 0ull;
        return;
    }
    float x1 = sx1[i], y1 = sy1[i], x2 = sx2[i], y2 = sy2[i];
    float ai = (x2 - x1) * (y2 - y1);
    u64 word = 0;
#pragma unroll 8
    for (int e = 0; e < 1024; ++e) {
        int j = jc * 1024 + e;
        const Box8 bj = sbox[j];   // wave-uniform -> s_load
        float xx1 = fmaxf(x1, bj.x1);
        float yy1 = fmaxf(y1, bj.y1);
        float xx2 = fminf(x2, bj.x2);
        float yy2 = fminf(y2, bj.y2);
        float iw = fmaxf(xx2 - xx1, 0.f);
        float ih = fmaxf(yy2 - yy1, 0.f);
        float inter = iw * ih;
        float uni = ai + bj.a - inter;
        bool sup = (inter > 0.7f * uni) && (j > i) && (j < PRE_TOPK);
        word |= ((u64)sup) << (e & 63);
        if ((e & 63) == 63) {
            rowp[e >> 6] = word;
            if ((jc * 16 + (e >> 6)) == (i >> 6)) selfw[i] = word;
            word = 0;
        }
    }
}

// ---------------------------------------------------------------------------
// K5: word-batched greedy NMS scan (batch 16); initial removed bits from sInv;
// zero-fills output tail.
// ---------------------------------------------------------------------------
__global__ __launch_bounds__(64) void k5_scan(const u64* __restrict__ rows,
                                              const u64* __restrict__ selfw,
                                              const u32* __restrict__ sInv,
                                              const float* __restrict__ sS,
                                              const float* __restrict__ sx1, const float* __restrict__ sy1,
                                              const float* __restrict__ sx2, const float* __restrict__ sy2,
                                              float* __restrict__ out)
{
    __shared__ int keptList[2000];
    __shared__ int kcnt;
    int l = threadIdx.x;
    auto bw = [&](int w) -> u64 {
        const uint4* p = (const uint4*)(sInv + (size_t)w * 64);
        u64 v = 0;
#pragma unroll
        for (int j = 0; j < 16; ++j) {
            uint4 q = p[j];
            v |= ((u64)(q.x != 0) << (j * 4))     | ((u64)(q.y != 0) << (j * 4 + 1))
               | ((u64)(q.z != 0) << (j * 4 + 2)) | ((u64)(q.w != 0) << (j * 4 + 3));
        }
        return v;
    };
    u64 r0 = bw(l);
    u64 r1 = bw(64 + l);
    u64 r2 = (l < 32) ? bw(128 + l) : ~0ull;
    u64 swreg = selfw[l];
    int cnt = 0;
    bool done = false;
    for (int w = 0; w < 157 && !done; ++w) {
        u64 swnext = (w < 156) ? selfw[(size_t)(w + 1) * 64 + l] : 0ull;
        int slot = w >> 6, owner = w & 63;
        u64 val = (slot == 0) ? r0 : (slot == 1) ? r1 : r2;
        u64 rw = __shfl(val, owner, 64);
        u64 wmask = (w == 156) ? 0xFFFFull : ~0ull;
        u64 av = (~rw) & wmask;
        u64 km = 0;
        while (av) {                     // intra-word resolve, registers only
            int b = __ffsll((unsigned long long)av) - 1;
            u64 sw = __shfl(swreg, b, 64);
            km |= 1ull << b;
            av &= ~(1ull << b);
            av &= ~sw;
        }
        u64 kk = km;
        while (kk) {                     // OR kept rows, 16 per batch
            int bsx[16];
            int nb = 0;
            while (kk && nb < 16) {
                int b = __ffsll((unsigned long long)kk) - 1;
                kk &= kk - 1;
                bsx[nb++] = b;
            }
            u64 a0 = 0, a1 = 0, a2 = 0;
#pragma unroll
            for (int u = 0; u < 16; ++u) {
                if (u < nb) {
                    int i = (w << 6) + bsx[u];
                    if (l == 0 && cnt + u < 2000) keptList[cnt + u] = i;
                    const u64* rp = rows + (size_t)i * NWORDS;
                    a0 |= rp[l];
                    a1 |= rp[64 + l];
                    if (l < 32) a2 |= rp[128 + l];
                }
            }
            r0 |= a0; r1 |= a1; r2 |= a2;
            cnt += nb;
            if (cnt >= 2000) { done = true; break; }
        }
        swreg = swnext;
    }
    if (l == 0) kcnt = (cnt < 2000) ? cnt : 2000;
    __syncthreads();
    int K = kcnt;
    for (int r = l; r < 2000; r += 64) {
        if (r < K) {
            int j = keptList[r];
            out[r * 4 + 0] = sx1[j];
            out[r * 4 + 1] = sy1[j];
            out[r * 4 + 2] = sx2[j];
            out[r * 4 + 3] = sy2[j];
            out[8000 + r]  = sS[j];
        } else {
            out[r * 4 + 0] = 0.f; out[r * 4 + 1] = 0.f;
            out[r * 4 + 2] = 0.f; out[r * 4 + 3] = 0.f;
            out[8000 + r]  = 0.f;
        }
    }
}

// ---------------------------------------------------------------------------
extern "C" void kernel_launch(void* const* d_in, const int* in_sizes, int n_in,
                              void* d_out, int out_size, void* d_ws, size_t ws_size,
                              hipStream_t stream)
{
    (void)in_sizes; (void)n_in; (void)out_size;
    const float* feat = (const float*)d_in[1];
    const float* wrpn = (const float*)d_in[3];
    const float* brpn = (const float*)d_in[4];
    const float* wcls = (const float*)d_in[5];
    const float* bcls = (const float*)d_in[6];
    const float* wreg = (const float*)d_in[7];
    const float* breg = (const float*)d_in[8];
    float* out = (float*)d_out;

    // K-split factor by workspace budget. need(ns) = ns*512*2560*4 + 16,252,928.
    int ns = (ws_size >= 58195968) ? 8 : (ws_size >= 37224448) ? 4 : 2;
    int cper = 16 / ns;
    int cperLog = (ns == 2) ? 3 : (ns == 4) ? 2 : 1;
    size_t pkB = (size_t)ns * 512 * 2560 * 4;

    char* ws = (char*)d_ws;
    // Live ranges:
    //   [0,pkB)            pk     k1m..k2a
    //   [pkB,pkB+16.25M)   Xt+W   kprep..k1m; then smalls (k2a+), part
    //                      (k2a..k2b) and rows (k4..k5) — part/rows share
    //                      the same offset (disjoint lifetimes).
    float* pk = (float*)ws;
    unsigned short* Xthi = (unsigned short*)(ws + pkB);
    unsigned short* Xtlo = Xthi + (size_t)52 * 64 * 512;
    unsigned short* Whi  = (unsigned short*)(ws + pkB + 6815744);
    unsigned short* Wlo  = Whi + (size_t)512 * 4608;

    char* sm = ws + pkB;
    float* score = (float*)(sm + 0);             // 90,000
    float* bx1   = (float*)(sm + 90000);
    float* by1   = (float*)(sm + 180000);
    float* bx2   = (float*)(sm + 270000);
    float* by2   = (float*)(sm + 360000);
    u32*   valid = (u32*)  (sm + 450000);        // 90,000
    u64*   key   = (u64*)  (sm + 540000);        // 180,000
    u32*   rankp = (u32*)  (sm + 720000);        // 810,000 (9 chunks)
    float* sS    = (float*)(sm + 1530000);       // 40,000
    float* sx1   = (float*)(sm + 1570000);
    float* sy1   = (float*)(sm + 1610000);
    float* sx2   = (float*)(sm + 1650000);
    float* sy2   = (float*)(sm + 1690000);
    u32*   sInv  = (u32*)  (sm + 1730000);       // 40,960
    u64*   selfw = (u64*)  (sm + 1770960);       // 81,920
    Box8*  sbox  = (Box8*) (sm + 1852880);       // 327,680 (10240 entries)
    float* part  = (float*)(sm + 2180560);       // 3,600,000 (k2a..k2b)
    u64*   rows  = (u64*)  (sm + 2180560);       // 12,800,000 (k4..k5) -> ends sm+14.98M < 16.25M
    // peak footprint = pkB + 16,252,928 (ns=4 -> 37.2 MB, proven available)

    AnchorBase ab;
    {
        const float scales[3] = {128.f, 256.f, 512.f};
        const float aspect[3] = {0.5f, 1.f, 2.f};
        for (int ai = 0; ai < 3; ++ai) {
            float hr = sqrtf(aspect[ai]);
            float wratio = 1.0f / hr;
            for (int si = 0; si < 3; ++si) {
                float wsz = wratio * scales[si];
                float hsz = hr * scales[si];
                int a = ai * 3 + si;
                ab.b[a * 4 + 0] = rintf(-wsz / 2.0f);
                ab.b[a * 4 + 1] = rintf(-hsz / 2.0f);
                ab.b[a * 4 + 2] = rintf( wsz / 2.0f);
                ab.b[a * 4 + 3] = rintf( hsz / 2.0f);
            }
        }
    }

    kprep    <<<928, 256, 0, stream>>>(feat, wrpn, Xthi, Xtlo, Whi, Wlo);
    k1m      <<<dim3(40, 8, ns), 256, 0, stream>>>(Xthi, Xtlo, Whi, Wlo, pk, cper, cperLog);
    k2a_heads<<<dim3(40, 8), 256, 0, stream>>>(pk, ns, brpn, wcls, wreg, part);
    k2b_decode<<<88, 256, 0, stream>>>(part, bcls, breg, ab, score, bx1, by1, bx2, by2, valid, key);
    k3a_rank <<<dim3(88, 9), 256, 0, stream>>>(key, rankp);
    k3b_gather<<<88, 256, 0, stream>>>(rankp, score, bx1, by1, bx2, by2, valid,
                                       sS, sx1, sy1, sx2, sy2, sbox, sInv);
    k4_mat   <<<dim3(40, 10), 256, 0, stream>>>(sx1, sy1, sx2, sy2, sbox, rows, selfw);
    k5_scan  <<<1, 64, 0, stream>>>(rows, selfw, sInv, sS, sx1, sy1, sx2, sy2, out);
}

// Round 7
// 583.546 us; speedup vs baseline: 1.1288x; 1.1288x over previous
//
#include <hip/hip_runtime.h>
#include <cmath>
#include <cstdint>
#include <cstddef>

typedef unsigned long long u64;
typedef unsigned int u32;

#define NPX   2500
#define NANCH 22500
#define PRE_TOPK 10000
#define NWORDS 160      // 160*64 = 10240 bits per NMS row

struct AnchorBase { float b[36]; };

typedef __attribute__((ext_vector_type(8))) short bf16x8;
typedef __attribute__((ext_vector_type(4))) float f32x4;

__device__ inline unsigned short f2bf(float f) {
    u32 u = __float_as_uint(f);
    u32 r = u + 0x7fffu + ((u >> 16) & 1u);
    return (unsigned short)(r >> 16);
}
__device__ inline float bf2f(unsigned short h) {
    return __uint_as_float(((u32)h) << 16);
}

// ---------------------------------------------------------------------------
// KPREP: fused input prep (Xt bf16 hi/lo padded grid; W' bf16 hi/lo).
// ---------------------------------------------------------------------------
__global__ __launch_bounds__(256) void kprep(const float* __restrict__ feat,
                                             const float* __restrict__ wr,
                                             unsigned short* __restrict__ xthi,
                                             unsigned short* __restrict__ xtlo,
                                             unsigned short* __restrict__ whi,
                                             unsigned short* __restrict__ wlo)
{
    __shared__ float sh[4608];
    int bid = blockIdx.x;
    int t = threadIdx.x;
    if (bid < 416) {
        float (*tile)[65] = (float(*)[65])sh;
        int gr = bid >> 3;          // grid row 0..51
        int cc = bid & 7;           // c-chunk
        int tx = t & 63, ty = t >> 6;
        int y = gr - 1;
        bool rowok = (gr >= 1) && (gr <= 50);
#pragma unroll
        for (int i = 0; i < 16; ++i) {
            int c = i * 4 + ty;
            tile[c][tx] = (rowok && tx < 50)
                        ? feat[(size_t)(cc * 64 + c) * NPX + y * 50 + tx] : 0.f;
        }
        __syncthreads();
#pragma unroll
        for (int i = 0; i < 16; ++i) {
            int xp = i * 4 + ty;
            int cell = gr * 64 + xp;
            bool ok = rowok && xp >= 1 && xp <= 50;
            float v = ok ? tile[tx][xp - 1] : 0.f;
            unsigned short hi = f2bf(v);
            xthi[(size_t)cell * 512 + cc * 64 + tx] = hi;
            xtlo[(size_t)cell * 512 + cc * 64 + tx] = f2bf(v - bf2f(hi));
        }
    } else {
        int oc = bid - 416;         // 0..511
        for (int j = t; j < 4608; j += 256) sh[j] = wr[(size_t)oc * 4608 + j];
        __syncthreads();
        for (int k = t; k < 4608; k += 256) {
            int c = k & 511, tap = k >> 9;
            float v = sh[c * 9 + tap];
            unsigned short hi = f2bf(v);
            whi[(size_t)oc * 4608 + k] = hi;
            wlo[(size_t)oc * 4608 + k] = f2bf(v - bf2f(hi));
        }
    }
}

// ---------------------------------------------------------------------------
// K1m v4: conv as bf16x3 MFMA GEMM. Wave = 32oc x 32px; block = 64oc x 64px.
// Grid (40, 8, ns).
// ---------------------------------------------------------------------------
struct Frag { bf16x8 ah0, ah1, al0, al1, bh0, bh1, bl0, bl1; };

__device__ inline void k1_load(Frag& F, int it, int cperm1, int cperLog, int chb,
                               int quad, int p0, int p1,
                               size_t wrow0, size_t wrow1,
                               const unsigned short* __restrict__ xthi,
                               const unsigned short* __restrict__ xtlo,
                               const unsigned short* __restrict__ whi,
                               const unsigned short* __restrict__ wlo)
{
    int tap = it >> cperLog;
    int cw  = it & cperm1;
    int kq  = (chb + cw) * 32 + quad * 8;
    int kw  = tap * 512 + kq;
    int t3  = (tap * 43) >> 7;             // tap/3
    int tapoff = (t3 - 1) * 64 + (tap - t3 * 3) - 1;
    F.ah0 = *(const bf16x8*)(whi + wrow0 + kw);
    F.ah1 = *(const bf16x8*)(whi + wrow1 + kw);
    F.al0 = *(const bf16x8*)(wlo + wrow0 + kw);
    F.al1 = *(const bf16x8*)(wlo + wrow1 + kw);
    size_t o0 = (size_t)(p0 + tapoff) * 512 + kq;
    size_t o1 = (size_t)(p1 + tapoff) * 512 + kq;
    F.bh0 = *(const bf16x8*)(xthi + o0);
    F.bh1 = *(const bf16x8*)(xthi + o1);
    F.bl0 = *(const bf16x8*)(xtlo + o0);
    F.bl1 = *(const bf16x8*)(xtlo + o1);
}

__device__ inline void k1_step(const Frag& F, f32x4* a)
{
#define MF(d, A, B) d = __builtin_amdgcn_mfma_f32_16x16x32_bf16(F.A, F.B, d, 0, 0, 0)
    MF(a[0], al0, bh0); MF(a[0], ah0, bl0); MF(a[0], ah0, bh0);
    MF(a[1], al0, bh1); MF(a[1], ah0, bl1); MF(a[1], ah0, bh1);
    MF(a[2], al1, bh0); MF(a[2], ah1, bl0); MF(a[2], ah1, bh0);
    MF(a[3], al1, bh1); MF(a[3], ah1, bl1); MF(a[3], ah1, bh1);
#undef MF
}

__global__ __launch_bounds__(256) void k1m(const unsigned short* __restrict__ xthi,
                                           const unsigned short* __restrict__ xtlo,
                                           const unsigned short* __restrict__ whi,
                                           const unsigned short* __restrict__ wlo,
                                           float* __restrict__ pk,
                                           int cper, int cperLog)
{
    int t = threadIdx.x;
    int lane = t & 63, wave = t >> 6;
    int wo = wave & 1, wp = wave >> 1;
    int pb = blockIdx.x, ob = blockIdx.y, bs = blockIdx.z;
    int quad = lane >> 4, m = lane & 15;
    int ocbase = ob * 64 + wo * 32;
    int pxbase = pb * 64 + wp * 32;
    int chb = bs * cper;
    int cperm1 = cper - 1;

    int prow[2];
#pragma unroll
    for (int sp = 0; sp < 2; ++sp) {
        int opx = pxbase + sp * 16 + m;
        prow[sp] = (opx < NPX) ? ((opx / 50) + 1) * 64 + (opx % 50) + 1 : 190;
    }
    size_t wrow0 = (size_t)(ocbase + m) * 4608;
    size_t wrow1 = wrow0 + (size_t)16 * 4608;

    f32x4 acc[4];
    f32x4 zf = {0.f, 0.f, 0.f, 0.f};
#pragma unroll
    for (int i = 0; i < 4; ++i) acc[i] = zf;

    int niter = 9 * cper;   // 18 / 36 / 72, always even
    Frag F0, F1;
    k1_load(F0, 0, cperm1, cperLog, chb, quad, prow[0], prow[1],
            wrow0, wrow1, xthi, xtlo, whi, wlo);
    for (int it = 0; it < niter; it += 2) {
        k1_load(F1, it + 1, cperm1, cperLog, chb, quad, prow[0], prow[1],
                wrow0, wrow1, xthi, xtlo, whi, wlo);
        k1_step(F0, acc);
        if (it + 2 < niter)
            k1_load(F0, it + 2, cperm1, cperLog, chb, quad, prow[0], prow[1],
                    wrow0, wrow1, xthi, xtlo, whi, wlo);
        k1_step(F1, acc);
    }
    // C/D: col(px)=lane&15, row(oc)=quad*4+reg
#pragma unroll
    for (int so = 0; so < 2; ++so)
#pragma unroll
        for (int sp = 0; sp < 2; ++sp)
#pragma unroll
            for (int r = 0; r < 4; ++r) {
                int oc = ocbase + so * 16 + quad * 4 + r;
                int px = pxbase + sp * 16 + m;
                pk[((size_t)bs * 512 + oc) * 2560 + px] = acc[so * 2 + sp][r];
            }
}

// ---------------------------------------------------------------------------
// K2a: fused k-split reduce + bias + ReLU + 1x1 heads partial GEMM.
// Grid (40 px-tiles, 8 c-chunks) = 320 blocks.
// ---------------------------------------------------------------------------
__global__ __launch_bounds__(256) void k2a_heads(const float* __restrict__ pk, int ns,
                                                 const float* __restrict__ br,
                                                 const float* __restrict__ wcls,
                                                 const float* __restrict__ wreg,
                                                 float* __restrict__ part)
{
    __shared__ float vt[64 * 64];
    __shared__ float Wl[45 * 64];
    int t  = threadIdx.x;
    int pb = blockIdx.x;           // 0..39
    int s  = blockIdx.y;           // 0..7
    int cb = s * 64;
    for (int e = t; e < 45 * 64; e += 256) {
        int u = e >> 6, c = e & 63;
        Wl[e] = (u < 9) ? wcls[u * 512 + cb + c] : wreg[(u - 9) * 512 + cb + c];
    }
    int pxl = t & 63, ug = t >> 6;
    int px = pb * 64 + pxl;
    bool ok = px < NPX;
#pragma unroll
    for (int i = 0; i < 16; ++i) {
        int c = ug * 16 + i;       // wave-uniform
        float v = 0.f;
        if (ok) {
            size_t bidx = (size_t)(cb + c) * 2560 + px;
            v = br[cb + c];
            for (int ks = 0; ks < ns; ++ks) v += pk[(size_t)ks * 512 * 2560 + bidx];
            v = v > 0.f ? v : 0.f;
        }
        vt[c * 64 + pxl] = v;
    }
    __syncthreads();
    int ubase = ug * 12;
    int ulim  = (45 - ubase < 12) ? (45 - ubase) : 12;
    float acc[12];
#pragma unroll
    for (int j = 0; j < 12; ++j) acc[j] = 0.f;
    for (int c = 0; c < 64; ++c) {
        float v = vt[c * 64 + pxl];
#pragma unroll
        for (int j = 0; j < 12; ++j)
            acc[j] = fmaf(v, Wl[(ubase + j) * 64 + c], acc[j]);
    }
    if (ok) {
        for (int j = 0; j < ulim; ++j)
            part[((size_t)s * 45 + ubase + j) * NPX + px] = acc[j];
    }
}

// ---------------------------------------------------------------------------
// K2b: reduce partials + bias, sigmoid, decode, clip, validity, sort key.
// ---------------------------------------------------------------------------
__global__ __launch_bounds__(256) void k2b_decode(const float* __restrict__ part,
                                                  const float* __restrict__ bcls,
                                                  const float* __restrict__ breg,
                                                  AnchorBase ab,
                                                  float* __restrict__ score,
                                                  float* __restrict__ bx1, float* __restrict__ by1,
                                                  float* __restrict__ bx2, float* __restrict__ by2,
                                                  u32* __restrict__ valid,
                                                  u64* __restrict__ key)
{
    int id = blockIdx.x * 256 + threadIdx.x;
    if (id >= NANCH) return;
    int k  = id / NPX;
    int px = id - k * NPX;

    float z  = bcls[k];
    float d0 = breg[k * 4 + 0], d1 = breg[k * 4 + 1];
    float d2 = breg[k * 4 + 2], d3 = breg[k * 4 + 3];
#pragma unroll
    for (int s = 0; s < 8; ++s) {
        const float* p = part + (size_t)s * 45 * NPX;
        z  += p[(size_t)k * NPX + px];
        d0 += p[(size_t)(9 + k * 4 + 0) * NPX + px];
        d1 += p[(size_t)(9 + k * 4 + 1) * NPX + px];
        d2 += p[(size_t)(9 + k * 4 + 2) * NPX + px];
        d3 += p[(size_t)(9 + k * 4 + 3) * NPX + px];
    }
    float sc = 1.f / (1.f + expf(-z));

    int yy = px / 50, xx = px - (px / 50) * 50;
    float fx = (float)xx, fy = (float)yy;
    float ax1 = fx + ab.b[k * 4 + 0], ay1 = fy + ab.b[k * 4 + 1];
    float ax2 = fx + ab.b[k * 4 + 2], ay2 = fy + ab.b[k * 4 + 3];
    float aw = ax2 - ax1, ah = ay2 - ay1;
    float cx = ax1 + 0.5f * aw, cy = ay1 + 0.5f * ah;
    float pcx = d0 * aw + cx, pcy = d1 * ah + cy;
    float pw = expf(d2) * aw, ph = expf(d3) * ah;
    float x1 = pcx - 0.5f * pw, y1 = pcy - 0.5f * ph;
    float x2 = pcx + 0.5f * pw, y2 = pcy + 0.5f * ph;
    x1 = fminf(fmaxf(x1, 0.f), 800.f);
    y1 = fminf(fmaxf(y1, 0.f), 800.f);
    x2 = fminf(fmaxf(x2, 0.f), 800.f);
    y2 = fminf(fmaxf(y2, 0.f), 800.f);
    u32 v = ((x2 - x1) >= 16.f) && ((y2 - y1) >= 16.f);

    int f = px * 9 + k;
    score[f] = sc;
    bx1[f] = x1; by1[f] = y1; bx2[f] = x2; by2[f] = y2;
    valid[f] = v;
    u32 sb = __float_as_uint(sc);
    key[f] = ((u64)(~sb) << 32) | (u32)f;
}

// ---------------------------------------------------------------------------
// K3a: partial ranks, LDS-staged (R5 version — R6's uniform VMEM loads
// serialized on L2 latency; HIP does NOT scalarize uniform loads).
// ---------------------------------------------------------------------------
__global__ __launch_bounds__(256) void k3a_rank(const u64* __restrict__ key,
                                                u32* __restrict__ rankp)
{
    __shared__ u64 sk[4500];
    int t  = threadIdx.x;
    int jb = blockIdx.y;           // 0..4
    for (int e = t; e < 4500; e += 256) sk[e] = key[jb * 4500 + e];
    __syncthreads();
    int i = blockIdx.x * 256 + t;
    if (i >= NANCH) return;
    u64 ki = key[i];
    u32 cnt = 0;
#pragma unroll 8
    for (int j = 0; j < 4500; ++j) cnt += (sk[j] < ki) ? 1u : 0u;
    rankp[(size_t)jb * NANCH + i] = cnt;
}

// ---------------------------------------------------------------------------
// K3b: sum 5 partial ranks, scatter top-10000; sInv[r] = 1 if invalid box.
// ---------------------------------------------------------------------------
__global__ __launch_bounds__(256) void k3b_gather(const u32* __restrict__ rankp,
                                                  const float* __restrict__ score,
                                                  const float* __restrict__ bx1, const float* __restrict__ by1,
                                                  const float* __restrict__ bx2, const float* __restrict__ by2,
                                                  const u32* __restrict__ valid,
                                                  float* __restrict__ sS,
                                                  float* __restrict__ sx1, float* __restrict__ sy1,
                                                  float* __restrict__ sx2, float* __restrict__ sy2,
                                                  u32* __restrict__ sInv)
{
    int i = blockIdx.x * 256 + threadIdx.x;
    if (i >= NANCH) return;
    u32 r = rankp[i] + rankp[NANCH + i] + rankp[2 * NANCH + i]
          + rankp[3 * NANCH + i] + rankp[4 * NANCH + i];
    if (r >= PRE_TOPK) return;
    sS[r] = score[i];
    sx1[r] = bx1[i]; sy1[r] = by1[i]; sx2[r] = bx2[i]; sy2[r] = by2[i];
    sInv[r] = valid[i] ? 0u : 1u;
}

// ---------------------------------------------------------------------------
// K4 v3: ballot-transpose suppression matrix. Lanes = j (boxes in REGISTERS,
// loaded once, coalesced); i streamed from LDS broadcasts; one __ballot per
// (i, j-word) emits a full 64-bit row word. Scalar mask handles j>i and
// j<PRE_TOPK. Each wave owns 2 j-words; block = 4 waves = 8 words.
// Grid (40 i-chunks of 256, 20 word-groups of 8).
// ---------------------------------------------------------------------------
__global__ __launch_bounds__(256) void k4_mat(const float* __restrict__ sx1, const float* __restrict__ sy1,
                                              const float* __restrict__ sx2, const float* __restrict__ sy2,
                                              u64* __restrict__ rows,
                                              u64* __restrict__ selfw)
{
    __shared__ float4 ib4[256];
    __shared__ float  ibA[256];
    int t = threadIdx.x, lane = t & 63, wave = t >> 6;
    int i0 = blockIdx.x * 256;
    int jw0 = blockIdx.y * 8 + wave * 2;      // this wave's 2 words

    // stage i-boxes (coalesced)
    {
        int gi = i0 + t;
        float4 b4 = {0.f, 0.f, 0.f, 0.f};
        float a = 0.f;
        if (gi < PRE_TOPK) {
            b4.x = sx1[gi]; b4.y = sy1[gi]; b4.z = sx2[gi]; b4.w = sy2[gi];
            a = (b4.z - b4.x) * (b4.w - b4.y);
        }
        ib4[t] = b4; ibA[t] = a;
    }
    // per-lane j-boxes for 2 words (j up to 10239 reads trailing garbage —
    // masked off below; stays inside workspace)
    float jx1[2], jy1[2], jx2[2], jy2[2], ja[2];
#pragma unroll
    for (int wsel = 0; wsel < 2; ++wsel) {
        int j = (jw0 + wsel) * 64 + lane;
        float a1 = sx1[j], b1 = sy1[j], a2 = sx2[j], b2 = sy2[j];
        jx1[wsel] = a1; jy1[wsel] = b1; jx2[wsel] = a2; jy2[wsel] = b2;
        ja[wsel] = (a2 - a1) * (b2 - b1);
    }
    __syncthreads();

    int imax = PRE_TOPK - i0;
    if (imax > 256) imax = 256;
    for (int ii = 0; ii < imax; ++ii) {
        int i = i0 + ii;
        // scalar masks for both words
        u64 msk[2];
#pragma unroll
        for (int wsel = 0; wsel < 2; ++wsel) {
            int jw = jw0 + wsel;
            int lo = jw * 64;
            u64 m = (i < lo) ? ~0ull
                  : ((i - lo >= 63) ? 0ull : ~((2ull << (i - lo)) - 1ull));
            u64 jmask = (jw < 156) ? ~0ull : ((jw == 156) ? 0xFFFFull : 0ull);
            msk[wsel] = m & jmask;
        }
        u64 w0 = 0, w1 = 0;
        if (msk[0] | msk[1]) {
            float4 bi = ib4[ii];          // LDS broadcast
            float ai = ibA[ii];
#pragma unroll
            for (int wsel = 0; wsel < 2; ++wsel) {
                if (!msk[wsel]) continue;
                float xx1 = fmaxf(bi.x, jx1[wsel]);
                float yy1 = fmaxf(bi.y, jy1[wsel]);
                float xx2 = fminf(bi.z, jx2[wsel]);
                float yy2 = fminf(bi.w, jy2[wsel]);
                float iw = fmaxf(xx2 - xx1, 0.f);
                float ih = fmaxf(yy2 - yy1, 0.f);
                float inter = iw * ih;
                float uni = ai + ja[wsel] - inter;
                u64 b = __ballot(inter > 0.7f * uni) & msk[wsel];
                if (wsel == 0) w0 = b; else w1 = b;
            }
        }
        if (lane == 0) {
            rows[(size_t)i * NWORDS + jw0]     = w0;
            rows[(size_t)i * NWORDS + jw0 + 1] = w1;
            int sw = i >> 6;
            if (sw == jw0)     selfw[i] = w0;
            if (sw == jw0 + 1) selfw[i] = w1;
        }
    }
}

// ---------------------------------------------------------------------------
// K5: word-batched greedy NMS scan (batch 16); initial removed bits from sInv;
// zero-fills output tail.
// ---------------------------------------------------------------------------
__global__ __launch_bounds__(64) void k5_scan(const u64* __restrict__ rows,
                                              const u64* __restrict__ selfw,
                                              const u32* __restrict__ sInv,
                                              const float* __restrict__ sS,
                                              const float* __restrict__ sx1, const float* __restrict__ sy1,
                                              const float* __restrict__ sx2, const float* __restrict__ sy2,
                                              float* __restrict__ out)
{
    __shared__ int keptList[2000];
    __shared__ int kcnt;
    int l = threadIdx.x;
    auto bw = [&](int w) -> u64 {
        const uint4* p = (const uint4*)(sInv + (size_t)w * 64);
        u64 v = 0;
#pragma unroll
        for (int j = 0; j < 16; ++j) {
            uint4 q = p[j];
            v |= ((u64)(q.x != 0) << (j * 4))     | ((u64)(q.y != 0) << (j * 4 + 1))
               | ((u64)(q.z != 0) << (j * 4 + 2)) | ((u64)(q.w != 0) << (j * 4 + 3));
        }
        return v;
    };
    u64 r0 = bw(l);
    u64 r1 = bw(64 + l);
    u64 r2 = (l < 32) ? bw(128 + l) : ~0ull;
    u64 swreg = selfw[l];
    int cnt = 0;
    bool done = false;
    for (int w = 0; w < 157 && !done; ++w) {
        u64 swnext = (w < 156) ? selfw[(size_t)(w + 1) * 64 + l] : 0ull;
        int slot = w >> 6, owner = w & 63;
        u64 val = (slot == 0) ? r0 : (slot == 1) ? r1 : r2;
        u64 rw = __shfl(val, owner, 64);
        u64 wmask = (w == 156) ? 0xFFFFull : ~0ull;
        u64 av = (~rw) & wmask;
        u64 km = 0;
        while (av) {                     // intra-word resolve, registers only
            int b = __ffsll((unsigned long long)av) - 1;
            u64 sw = __shfl(swreg, b, 64);
            km |= 1ull << b;
            av &= ~(1ull << b);
            av &= ~sw;
        }
        u64 kk = km;
        while (kk) {                     // OR kept rows, 16 per batch
            int bsx[16];
            int nb = 0;
            while (kk && nb < 16) {
                int b = __ffsll((unsigned long long)kk) - 1;
                kk &= kk - 1;
                bsx[nb++] = b;
            }
            u64 a0 = 0, a1 = 0, a2 = 0;
#pragma unroll
            for (int u = 0; u < 16; ++u) {
                if (u < nb) {
                    int i = (w << 6) + bsx[u];
                    if (l == 0 && cnt + u < 2000) keptList[cnt + u] = i;
                    const u64* rp = rows + (size_t)i * NWORDS;
                    a0 |= rp[l];
                    a1 |= rp[64 + l];
                    if (l < 32) a2 |= rp[128 + l];
                }
            }
            r0 |= a0; r1 |= a1; r2 |= a2;
            cnt += nb;
            if (cnt >= 2000) { done = true; break; }
        }
        swreg = swnext;
    }
    if (l == 0) kcnt = (cnt < 2000) ? cnt : 2000;
    __syncthreads();
    int K = kcnt;
    for (int r = l; r < 2000; r += 64) {
        if (r < K) {
            int j = keptList[r];
            out[r * 4 + 0] = sx1[j];
            out[r * 4 + 1] = sy1[j];
            out[r * 4 + 2] = sx2[j];
            out[r * 4 + 3] = sy2[j];
            out[8000 + r]  = sS[j];
        } else {
            out[r * 4 + 0] = 0.f; out[r * 4 + 1] = 0.f;
            out[r * 4 + 2] = 0.f; out[r * 4 + 3] = 0.f;
            out[8000 + r]  = 0.f;
        }
    }
}

// ---------------------------------------------------------------------------
extern "C" void kernel_launch(void* const* d_in, const int* in_sizes, int n_in,
                              void* d_out, int out_size, void* d_ws, size_t ws_size,
                              hipStream_t stream)
{
    (void)in_sizes; (void)n_in; (void)out_size;
    const float* feat = (const float*)d_in[1];
    const float* wrpn = (const float*)d_in[3];
    const float* brpn = (const float*)d_in[4];
    const float* wcls = (const float*)d_in[5];
    const float* bcls = (const float*)d_in[6];
    const float* wreg = (const float*)d_in[7];
    const float* breg = (const float*)d_in[8];
    float* out = (float*)d_out;

    // K-split factor by workspace budget. need(ns) = ns*512*2560*4 + 16,252,928.
    int ns = (ws_size >= 58195968) ? 8 : (ws_size >= 37224448) ? 4 : 2;
    int cper = 16 / ns;
    int cperLog = (ns == 2) ? 3 : (ns == 4) ? 2 : 1;
    size_t pkB = (size_t)ns * 512 * 2560 * 4;

    char* ws = (char*)d_ws;
    // Live ranges:
    //   [0,pkB)            pk     k1m..k2a
    //   [pkB,pkB+16.25M)   Xt+W   kprep..k1m; then smalls (k2a+), part
    //                      (k2a..k2b) and rows (k4..k5) share offsets.
    float* pk = (float*)ws;
    unsigned short* Xthi = (unsigned short*)(ws + pkB);
    unsigned short* Xtlo = Xthi + (size_t)52 * 64 * 512;
    unsigned short* Whi  = (unsigned short*)(ws + pkB + 6815744);
    unsigned short* Wlo  = Whi + (size_t)512 * 4608;

    char* sm = ws + pkB;
    float* score = (float*)(sm + 0);             // 90,000
    float* bx1   = (float*)(sm + 90000);
    float* by1   = (float*)(sm + 180000);
    float* bx2   = (float*)(sm + 270000);
    float* by2   = (float*)(sm + 360000);
    u32*   valid = (u32*)  (sm + 450000);        // 90,000
    u64*   key   = (u64*)  (sm + 540000);        // 180,000
    u32*   rankp = (u32*)  (sm + 720000);        // 450,000 (5 chunks)
    float* sS    = (float*)(sm + 1170000);       // 40,000
    float* sx1   = (float*)(sm + 1210000);
    float* sy1   = (float*)(sm + 1250000);
    float* sx2   = (float*)(sm + 1290000);
    float* sy2   = (float*)(sm + 1330000);
    u32*   sInv  = (u32*)  (sm + 1370000);       // 40,960
    u64*   selfw = (u64*)  (sm + 1410960);       // 81,920
    float* part  = (float*)(sm + 1492880);       // 3,600,000 (k2a..k2b)
    u64*   rows  = (u64*)  (sm + 1492880);       // 12,800,000 (k4..k5) -> ends sm+14.29M < 16.25M
    // peak footprint = pkB + 16,252,928 (ns=4 -> 37.2 MB, proven available)

    AnchorBase ab;
    {
        const float scales[3] = {128.f, 256.f, 512.f};
        const float aspect[3] = {0.5f, 1.f, 2.f};
        for (int ai = 0; ai < 3; ++ai) {
            float hr = sqrtf(aspect[ai]);
            float wratio = 1.0f / hr;
            for (int si = 0; si < 3; ++si) {
                float wsz = wratio * scales[si];
                float hsz = hr * scales[si];
                int a = ai * 3 + si;
                ab.b[a * 4 + 0] = rintf(-wsz / 2.0f);
                ab.b[a * 4 + 1] = rintf(-hsz / 2.0f);
                ab.b[a * 4 + 2] = rintf( wsz / 2.0f);
                ab.b[a * 4 + 3] = rintf( hsz / 2.0f);
            }
        }
    }

    kprep    <<<928, 256, 0, stream>>>(feat, wrpn, Xthi, Xtlo, Whi, Wlo);
    k1m      <<<dim3(40, 8, ns), 256, 0, stream>>>(Xthi, Xtlo, Whi, Wlo, pk, cper, cperLog);
    k2a_heads<<<dim3(40, 8), 256, 0, stream>>>(pk, ns, brpn, wcls, wreg, part);
    k2b_decode<<<88, 256, 0, stream>>>(part, bcls, breg, ab, score, bx1, by1, bx2, by2, valid, key);
    k3a_rank <<<dim3(88, 5), 256, 0, stream>>>(key, rankp);
    k3b_gather<<<88, 256, 0, stream>>>(rankp, score, bx1, by1, bx2, by2, valid,
                                       sS, sx1, sy1, sx2, sy2, sInv);
    k4_mat   <<<dim3(40, 20), 256, 0, stream>>>(sx1, sy1, sx2, sy2, rows, selfw);
    k5_scan  <<<1, 64, 0, stream>>>(rows, selfw, sInv, sS, sx1, sy1, sx2, sy2, out);
}

// Round 8
// 554.390 us; speedup vs baseline: 1.1882x; 1.0526x over previous
//
#include <hip/hip_runtime.h>
#include <cmath>
#include <cstdint>
#include <cstddef>

typedef unsigned long long u64;
typedef unsigned int u32;

#define NPX   2500
#define NANCH 22500
#define PRE_TOPK 10000
#define NWORDS 160      // 160*64 = 10240 bits per NMS row

struct AnchorBase { float b[36]; };

typedef __attribute__((ext_vector_type(8))) short bf16x8;
typedef __attribute__((ext_vector_type(4))) float f32x4;

__device__ inline unsigned short f2bf(float f) {
    u32 u = __float_as_uint(f);
    u32 r = u + 0x7fffu + ((u >> 16) & 1u);
    return (unsigned short)(r >> 16);
}
__device__ inline float bf2f(unsigned short h) {
    return __uint_as_float(((u32)h) << 16);
}

// ---------------------------------------------------------------------------
// KPREP: fused input prep (Xt bf16 hi/lo padded grid; W' bf16 hi/lo).
// ---------------------------------------------------------------------------
__global__ __launch_bounds__(256) void kprep(const float* __restrict__ feat,
                                             const float* __restrict__ wr,
                                             unsigned short* __restrict__ xthi,
                                             unsigned short* __restrict__ xtlo,
                                             unsigned short* __restrict__ whi,
                                             unsigned short* __restrict__ wlo)
{
    __shared__ float sh[4608];
    int bid = blockIdx.x;
    int t = threadIdx.x;
    if (bid < 416) {
        float (*tile)[65] = (float(*)[65])sh;
        int gr = bid >> 3;          // grid row 0..51
        int cc = bid & 7;           // c-chunk
        int tx = t & 63, ty = t >> 6;
        int y = gr - 1;
        bool rowok = (gr >= 1) && (gr <= 50);
#pragma unroll
        for (int i = 0; i < 16; ++i) {
            int c = i * 4 + ty;
            tile[c][tx] = (rowok && tx < 50)
                        ? feat[(size_t)(cc * 64 + c) * NPX + y * 50 + tx] : 0.f;
        }
        __syncthreads();
#pragma unroll
        for (int i = 0; i < 16; ++i) {
            int xp = i * 4 + ty;
            int cell = gr * 64 + xp;
            bool ok = rowok && xp >= 1 && xp <= 50;
            float v = ok ? tile[tx][xp - 1] : 0.f;
            unsigned short hi = f2bf(v);
            xthi[(size_t)cell * 512 + cc * 64 + tx] = hi;
            xtlo[(size_t)cell * 512 + cc * 64 + tx] = f2bf(v - bf2f(hi));
        }
    } else {
        int oc = bid - 416;         // 0..511
        for (int j = t; j < 4608; j += 256) sh[j] = wr[(size_t)oc * 4608 + j];
        __syncthreads();
        for (int k = t; k < 4608; k += 256) {
            int c = k & 511, tap = k >> 9;
            float v = sh[c * 9 + tap];
            unsigned short hi = f2bf(v);
            whi[(size_t)oc * 4608 + k] = hi;
            wlo[(size_t)oc * 4608 + k] = f2bf(v - bf2f(hi));
        }
    }
}

// ---------------------------------------------------------------------------
// K1m v5: conv as bf16x3 MFMA GEMM, v3 tile (wave 32oc x 64px, block 64x128).
//  - __launch_bounds__(256,2): VGPR cap 256 so the F0/F1 double buffer can
//    actually live in registers (R5/R7 compiled at 56-80 VGPR -> pipeline
//    demoted -> loads serialized at ~700cyc each; that WAS the k1m wall).
//  - branchless steady-state prefetch (wrap-around redundant load at end).
//  - grid (8 ob, 20 pb, ns): linear block id mod 8 == ob -> each XCD keeps
//    one 64-oc weight slice (2.36 MB) L2-resident instead of all 9.4 MB.
// ---------------------------------------------------------------------------
struct Frag {
    bf16x8 ah0, ah1, al0, al1;
    bf16x8 bh0, bh1, bh2, bh3, bl0, bl1, bl2, bl3;
};

__device__ inline void k1_load(Frag& F, int it, int cperm1, int cperLog, int chb,
                               int quad, int p0, int p1, int p2, int p3,
                               size_t wrow0, size_t wrow1,
                               const unsigned short* __restrict__ xthi,
                               const unsigned short* __restrict__ xtlo,
                               const unsigned short* __restrict__ whi,
                               const unsigned short* __restrict__ wlo)
{
    int tap = it >> cperLog;
    int cw  = it & cperm1;
    int kq  = (chb + cw) * 32 + quad * 8;
    int kw  = tap * 512 + kq;
    int t3  = (tap * 43) >> 7;             // tap/3
    int tapoff = (t3 - 1) * 64 + (tap - t3 * 3) - 1;
    F.ah0 = *(const bf16x8*)(whi + wrow0 + kw);
    F.ah1 = *(const bf16x8*)(whi + wrow1 + kw);
    F.al0 = *(const bf16x8*)(wlo + wrow0 + kw);
    F.al1 = *(const bf16x8*)(wlo + wrow1 + kw);
    size_t o0 = (size_t)(p0 + tapoff) * 512 + kq;
    size_t o1 = (size_t)(p1 + tapoff) * 512 + kq;
    size_t o2 = (size_t)(p2 + tapoff) * 512 + kq;
    size_t o3 = (size_t)(p3 + tapoff) * 512 + kq;
    F.bh0 = *(const bf16x8*)(xthi + o0);
    F.bh1 = *(const bf16x8*)(xthi + o1);
    F.bh2 = *(const bf16x8*)(xthi + o2);
    F.bh3 = *(const bf16x8*)(xthi + o3);
    F.bl0 = *(const bf16x8*)(xtlo + o0);
    F.bl1 = *(const bf16x8*)(xtlo + o1);
    F.bl2 = *(const bf16x8*)(xtlo + o2);
    F.bl3 = *(const bf16x8*)(xtlo + o3);
}

__device__ inline void k1_step(const Frag& F, f32x4* a)
{
#define MF(d, A, B) d = __builtin_amdgcn_mfma_f32_16x16x32_bf16(F.A, F.B, d, 0, 0, 0)
    MF(a[0], al0, bh0); MF(a[0], ah0, bl0); MF(a[0], ah0, bh0);
    MF(a[1], al0, bh1); MF(a[1], ah0, bl1); MF(a[1], ah0, bh1);
    MF(a[2], al0, bh2); MF(a[2], ah0, bl2); MF(a[2], ah0, bh2);
    MF(a[3], al0, bh3); MF(a[3], ah0, bl3); MF(a[3], ah0, bh3);
    MF(a[4], al1, bh0); MF(a[4], ah1, bl0); MF(a[4], ah1, bh0);
    MF(a[5], al1, bh1); MF(a[5], ah1, bl1); MF(a[5], ah1, bh1);
    MF(a[6], al1, bh2); MF(a[6], ah1, bl2); MF(a[6], ah1, bh2);
    MF(a[7], al1, bh3); MF(a[7], ah1, bl3); MF(a[7], ah1, bh3);
#undef MF
}

__global__ __launch_bounds__(256, 2) void k1m(const unsigned short* __restrict__ xthi,
                                              const unsigned short* __restrict__ xtlo,
                                              const unsigned short* __restrict__ whi,
                                              const unsigned short* __restrict__ wlo,
                                              float* __restrict__ pk,
                                              int cper, int cperLog)
{
    int t = threadIdx.x;
    int lane = t & 63, wave = t >> 6;
    int wo = wave & 1, wp = wave >> 1;
    int ob = blockIdx.x, pb = blockIdx.y, bs = blockIdx.z;   // x=ob: XCD swizzle
    int quad = lane >> 4, m = lane & 15;
    int ocbase = ob * 64 + wo * 32;
    int pxbase = pb * 128 + wp * 64;
    int chb = bs * cper;
    int cperm1 = cper - 1;

    int prow[4];
#pragma unroll
    for (int sp = 0; sp < 4; ++sp) {
        int opx = pxbase + sp * 16 + m;
        prow[sp] = (opx < NPX) ? ((opx / 50) + 1) * 64 + (opx % 50) + 1 : 190;
    }
    size_t wrow0 = (size_t)(ocbase + m) * 4608;
    size_t wrow1 = wrow0 + (size_t)16 * 4608;

    f32x4 acc[8];
    f32x4 zf = {0.f, 0.f, 0.f, 0.f};
#pragma unroll
    for (int i = 0; i < 8; ++i) acc[i] = zf;

    int niter = 9 * cper;   // 18 / 36 / 72, always even
    Frag F0, F1;
    k1_load(F0, 0, cperm1, cperLog, chb, quad, prow[0], prow[1], prow[2], prow[3],
            wrow0, wrow1, xthi, xtlo, whi, wlo);
    k1_load(F1, 1, cperm1, cperLog, chb, quad, prow[0], prow[1], prow[2], prow[3],
            wrow0, wrow1, xthi, xtlo, whi, wlo);
    for (int it = 0; it < niter; it += 2) {
        k1_step(F0, acc);
        int n0 = it + 2; if (n0 >= niter) n0 = 0;   // wrap: redundant, branchless
        k1_load(F0, n0, cperm1, cperLog, chb, quad, prow[0], prow[1], prow[2], prow[3],
                wrow0, wrow1, xthi, xtlo, whi, wlo);
        k1_step(F1, acc);
        int n1 = it + 3; if (n1 >= niter) n1 = 1;
        k1_load(F1, n1, cperm1, cperLog, chb, quad, prow[0], prow[1], prow[2], prow[3],
                wrow0, wrow1, xthi, xtlo, whi, wlo);
    }
    // C/D: col(px)=lane&15, row(oc)=quad*4+reg
#pragma unroll
    for (int so = 0; so < 2; ++so)
#pragma unroll
        for (int sp = 0; sp < 4; ++sp)
#pragma unroll
            for (int r = 0; r < 4; ++r) {
                int oc = ocbase + so * 16 + quad * 4 + r;
                int px = pxbase + sp * 16 + m;
                pk[((size_t)bs * 512 + oc) * 2560 + px] = acc[so * 4 + sp][r];
            }
}

// ---------------------------------------------------------------------------
// K2a: fused k-split reduce + bias + ReLU + 1x1 heads partial GEMM.
// Grid (40 px-tiles, 8 c-chunks) = 320 blocks.
// ---------------------------------------------------------------------------
__global__ __launch_bounds__(256) void k2a_heads(const float* __restrict__ pk, int ns,
                                                 const float* __restrict__ br,
                                                 const float* __restrict__ wcls,
                                                 const float* __restrict__ wreg,
                                                 float* __restrict__ part)
{
    __shared__ float vt[64 * 64];
    __shared__ float Wl[45 * 64];
    int t  = threadIdx.x;
    int pb = blockIdx.x;           // 0..39
    int s  = blockIdx.y;           // 0..7
    int cb = s * 64;
    for (int e = t; e < 45 * 64; e += 256) {
        int u = e >> 6, c = e & 63;
        Wl[e] = (u < 9) ? wcls[u * 512 + cb + c] : wreg[(u - 9) * 512 + cb + c];
    }
    int pxl = t & 63, ug = t >> 6;
    int px = pb * 64 + pxl;
    bool ok = px < NPX;
#pragma unroll
    for (int i = 0; i < 16; ++i) {
        int c = ug * 16 + i;       // wave-uniform
        float v = 0.f;
        if (ok) {
            size_t bidx = (size_t)(cb + c) * 2560 + px;
            v = br[cb + c];
            for (int ks = 0; ks < ns; ++ks) v += pk[(size_t)ks * 512 * 2560 + bidx];
            v = v > 0.f ? v : 0.f;
        }
        vt[c * 64 + pxl] = v;
    }
    __syncthreads();
    int ubase = ug * 12;
    int ulim  = (45 - ubase < 12) ? (45 - ubase) : 12;
    float acc[12];
#pragma unroll
    for (int j = 0; j < 12; ++j) acc[j] = 0.f;
    for (int c = 0; c < 64; ++c) {
        float v = vt[c * 64 + pxl];
#pragma unroll
        for (int j = 0; j < 12; ++j)
            acc[j] = fmaf(v, Wl[(ubase + j) * 64 + c], acc[j]);
    }
    if (ok) {
        for (int j = 0; j < ulim; ++j)
            part[((size_t)s * 45 + ubase + j) * NPX + px] = acc[j];
    }
}

// ---------------------------------------------------------------------------
// K2b: reduce partials + bias, sigmoid, decode, clip, validity, sort key.
// ---------------------------------------------------------------------------
__global__ __launch_bounds__(256) void k2b_decode(const float* __restrict__ part,
                                                  const float* __restrict__ bcls,
                                                  const float* __restrict__ breg,
                                                  AnchorBase ab,
                                                  float* __restrict__ score,
                                                  float* __restrict__ bx1, float* __restrict__ by1,
                                                  float* __restrict__ bx2, float* __restrict__ by2,
                                                  u32* __restrict__ valid,
                                                  u64* __restrict__ key)
{
    int id = blockIdx.x * 256 + threadIdx.x;
    if (id >= NANCH) return;
    int k  = id / NPX;
    int px = id - k * NPX;

    float z  = bcls[k];
    float d0 = breg[k * 4 + 0], d1 = breg[k * 4 + 1];
    float d2 = breg[k * 4 + 2], d3 = breg[k * 4 + 3];
#pragma unroll
    for (int s = 0; s < 8; ++s) {
        const float* p = part + (size_t)s * 45 * NPX;
        z  += p[(size_t)k * NPX + px];
        d0 += p[(size_t)(9 + k * 4 + 0) * NPX + px];
        d1 += p[(size_t)(9 + k * 4 + 1) * NPX + px];
        d2 += p[(size_t)(9 + k * 4 + 2) * NPX + px];
        d3 += p[(size_t)(9 + k * 4 + 3) * NPX + px];
    }
    float sc = 1.f / (1.f + expf(-z));

    int yy = px / 50, xx = px - (px / 50) * 50;
    float fx = (float)xx, fy = (float)yy;
    float ax1 = fx + ab.b[k * 4 + 0], ay1 = fy + ab.b[k * 4 + 1];
    float ax2 = fx + ab.b[k * 4 + 2], ay2 = fy + ab.b[k * 4 + 3];
    float aw = ax2 - ax1, ah = ay2 - ay1;
    float cx = ax1 + 0.5f * aw, cy = ay1 + 0.5f * ah;
    float pcx = d0 * aw + cx, pcy = d1 * ah + cy;
    float pw = expf(d2) * aw, ph = expf(d3) * ah;
    float x1 = pcx - 0.5f * pw, y1 = pcy - 0.5f * ph;
    float x2 = pcx + 0.5f * pw, y2 = pcy + 0.5f * ph;
    x1 = fminf(fmaxf(x1, 0.f), 800.f);
    y1 = fminf(fmaxf(y1, 0.f), 800.f);
    x2 = fminf(fmaxf(x2, 0.f), 800.f);
    y2 = fminf(fmaxf(y2, 0.f), 800.f);
    u32 v = ((x2 - x1) >= 16.f) && ((y2 - y1) >= 16.f);

    int f = px * 9 + k;
    score[f] = sc;
    bx1[f] = x1; by1[f] = y1; bx2[f] = x2; by2[f] = y2;
    valid[f] = v;
    u32 sb = __float_as_uint(sc);
    key[f] = ((u64)(~sb) << 32) | (u32)f;
}

// ---------------------------------------------------------------------------
// K3a: partial ranks, LDS-staged, b128 paired reads (halves DS-pipe issue).
// ---------------------------------------------------------------------------
__global__ __launch_bounds__(256) void k3a_rank(const u64* __restrict__ key,
                                                u32* __restrict__ rankp)
{
    __shared__ __align__(16) u64 sk[4500];
    int t  = threadIdx.x;
    int jb = blockIdx.y;           // 0..4
    for (int e = t; e < 4500; e += 256) sk[e] = key[jb * 4500 + e];
    __syncthreads();
    int i = blockIdx.x * 256 + t;
    if (i >= NANCH) return;
    u64 ki = key[i];
    const ulonglong2* sk2 = (const ulonglong2*)sk;
    u32 cnt = 0;
#pragma unroll 5
    for (int j = 0; j < 2250; ++j) {
        ulonglong2 v = sk2[j];
        cnt += (v.x < ki) ? 1u : 0u;
        cnt += (v.y < ki) ? 1u : 0u;
    }
    rankp[(size_t)jb * NANCH + i] = cnt;
}

// ---------------------------------------------------------------------------
// K3b: sum 5 partial ranks, scatter top-10000; sInv[r] = 1 if invalid box.
// ---------------------------------------------------------------------------
__global__ __launch_bounds__(256) void k3b_gather(const u32* __restrict__ rankp,
                                                  const float* __restrict__ score,
                                                  const float* __restrict__ bx1, const float* __restrict__ by1,
                                                  const float* __restrict__ bx2, const float* __restrict__ by2,
                                                  const u32* __restrict__ valid,
                                                  float* __restrict__ sS,
                                                  float* __restrict__ sx1, float* __restrict__ sy1,
                                                  float* __restrict__ sx2, float* __restrict__ sy2,
                                                  u32* __restrict__ sInv)
{
    int i = blockIdx.x * 256 + threadIdx.x;
    if (i >= NANCH) return;
    u32 r = rankp[i] + rankp[NANCH + i] + rankp[2 * NANCH + i]
          + rankp[3 * NANCH + i] + rankp[4 * NANCH + i];
    if (r >= PRE_TOPK) return;
    sS[r] = score[i];
    sx1[r] = bx1[i]; sy1[r] = by1[i]; sx2[r] = bx2[i]; sy2[r] = by2[i];
    sInv[r] = valid[i] ? 0u : 1u;
}

// ---------------------------------------------------------------------------
// K4 v3: ballot-transpose suppression matrix (R7 — verified).
// ---------------------------------------------------------------------------
__global__ __launch_bounds__(256) void k4_mat(const float* __restrict__ sx1, const float* __restrict__ sy1,
                                              const float* __restrict__ sx2, const float* __restrict__ sy2,
                                              u64* __restrict__ rows,
                                              u64* __restrict__ selfw)
{
    __shared__ float4 ib4[256];
    __shared__ float  ibA[256];
    int t = threadIdx.x, lane = t & 63, wave = t >> 6;
    int i0 = blockIdx.x * 256;
    int jw0 = blockIdx.y * 8 + wave * 2;      // this wave's 2 words

    {
        int gi = i0 + t;
        float4 b4 = {0.f, 0.f, 0.f, 0.f};
        float a = 0.f;
        if (gi < PRE_TOPK) {
            b4.x = sx1[gi]; b4.y = sy1[gi]; b4.z = sx2[gi]; b4.w = sy2[gi];
            a = (b4.z - b4.x) * (b4.w - b4.y);
        }
        ib4[t] = b4; ibA[t] = a;
    }
    float jx1[2], jy1[2], jx2[2], jy2[2], ja[2];
#pragma unroll
    for (int wsel = 0; wsel < 2; ++wsel) {
        int j = (jw0 + wsel) * 64 + lane;
        float a1 = sx1[j], b1 = sy1[j], a2 = sx2[j], b2 = sy2[j];
        jx1[wsel] = a1; jy1[wsel] = b1; jx2[wsel] = a2; jy2[wsel] = b2;
        ja[wsel] = (a2 - a1) * (b2 - b1);
    }
    __syncthreads();

    int imax = PRE_TOPK - i0;
    if (imax > 256) imax = 256;
    for (int ii = 0; ii < imax; ++ii) {
        int i = i0 + ii;
        u64 msk[2];
#pragma unroll
        for (int wsel = 0; wsel < 2; ++wsel) {
            int jw = jw0 + wsel;
            int lo = jw * 64;
            u64 m = (i < lo) ? ~0ull
                  : ((i - lo >= 63) ? 0ull : ~((2ull << (i - lo)) - 1ull));
            u64 jmask = (jw < 156) ? ~0ull : ((jw == 156) ? 0xFFFFull : 0ull);
            msk[wsel] = m & jmask;
        }
        u64 w0 = 0, w1 = 0;
        if (msk[0] | msk[1]) {
            float4 bi = ib4[ii];          // LDS broadcast
            float ai = ibA[ii];
#pragma unroll
            for (int wsel = 0; wsel < 2; ++wsel) {
                if (!msk[wsel]) continue;
                float xx1 = fmaxf(bi.x, jx1[wsel]);
                float yy1 = fmaxf(bi.y, jy1[wsel]);
                float xx2 = fminf(bi.z, jx2[wsel]);
                float yy2 = fminf(bi.w, jy2[wsel]);
                float iw = fmaxf(xx2 - xx1, 0.f);
                float ih = fmaxf(yy2 - yy1, 0.f);
                float inter = iw * ih;
                float uni = ai + ja[wsel] - inter;
                u64 b = __ballot(inter > 0.7f * uni) & msk[wsel];
                if (wsel == 0) w0 = b; else w1 = b;
            }
        }
        if (lane == 0) {
            rows[(size_t)i * NWORDS + jw0]     = w0;
            rows[(size_t)i * NWORDS + jw0 + 1] = w1;
            int sw = i >> 6;
            if (sw == jw0)     selfw[i] = w0;
            if (sw == jw0 + 1) selfw[i] = w1;
        }
    }
}

// ---------------------------------------------------------------------------
// K5: word-batched greedy NMS scan (batch 16); initial removed bits from sInv;
// zero-fills output tail.
// ---------------------------------------------------------------------------
__global__ __launch_bounds__(64) void k5_scan(const u64* __restrict__ rows,
                                              const u64* __restrict__ selfw,
                                              const u32* __restrict__ sInv,
                                              const float* __restrict__ sS,
                                              const float* __restrict__ sx1, const float* __restrict__ sy1,
                                              const float* __restrict__ sx2, const float* __restrict__ sy2,
                                              float* __restrict__ out)
{
    __shared__ int keptList[2000];
    __shared__ int kcnt;
    int l = threadIdx.x;
    auto bw = [&](int w) -> u64 {
        const uint4* p = (const uint4*)(sInv + (size_t)w * 64);
        u64 v = 0;
#pragma unroll
        for (int j = 0; j < 16; ++j) {
            uint4 q = p[j];
            v |= ((u64)(q.x != 0) << (j * 4))     | ((u64)(q.y != 0) << (j * 4 + 1))
               | ((u64)(q.z != 0) << (j * 4 + 2)) | ((u64)(q.w != 0) << (j * 4 + 3));
        }
        return v;
    };
    u64 r0 = bw(l);
    u64 r1 = bw(64 + l);
    u64 r2 = (l < 32) ? bw(128 + l) : ~0ull;
    u64 swreg = selfw[l];
    int cnt = 0;
    bool done = false;
    for (int w = 0; w < 157 && !done; ++w) {
        u64 swnext = (w < 156) ? selfw[(size_t)(w + 1) * 64 + l] : 0ull;
        int slot = w >> 6, owner = w & 63;
        u64 val = (slot == 0) ? r0 : (slot == 1) ? r1 : r2;
        u64 rw = __shfl(val, owner, 64);
        u64 wmask = (w == 156) ? 0xFFFFull : ~0ull;
        u64 av = (~rw) & wmask;
        u64 km = 0;
        while (av) {                     // intra-word resolve, registers only
            int b = __ffsll((unsigned long long)av) - 1;
            u64 sw = __shfl(swreg, b, 64);
            km |= 1ull << b;
            av &= ~(1ull << b);
            av &= ~sw;
        }
        u64 kk = km;
        while (kk) {                     // OR kept rows, 16 per batch
            int bsx[16];
            int nb = 0;
            while (kk && nb < 16) {
                int b = __ffsll((unsigned long long)kk) - 1;
                kk &= kk - 1;
                bsx[nb++] = b;
            }
            u64 a0 = 0, a1 = 0, a2 = 0;
#pragma unroll
            for (int u = 0; u < 16; ++u) {
                if (u < nb) {
                    int i = (w << 6) + bsx[u];
                    if (l == 0 && cnt + u < 2000) keptList[cnt + u] = i;
                    const u64* rp = rows + (size_t)i * NWORDS;
                    a0 |= rp[l];
                    a1 |= rp[64 + l];
                    if (l < 32) a2 |= rp[128 + l];
                }
            }
            r0 |= a0; r1 |= a1; r2 |= a2;
            cnt += nb;
            if (cnt >= 2000) { done = true; break; }
        }
        swreg = swnext;
    }
    if (l == 0) kcnt = (cnt < 2000) ? cnt : 2000;
    __syncthreads();
    int K = kcnt;
    for (int r = l; r < 2000; r += 64) {
        if (r < K) {
            int j = keptList[r];
            out[r * 4 + 0] = sx1[j];
            out[r * 4 + 1] = sy1[j];
            out[r * 4 + 2] = sx2[j];
            out[r * 4 + 3] = sy2[j];
            out[8000 + r]  = sS[j];
        } else {
            out[r * 4 + 0] = 0.f; out[r * 4 + 1] = 0.f;
            out[r * 4 + 2] = 0.f; out[r * 4 + 3] = 0.f;
            out[8000 + r]  = 0.f;
        }
    }
}

// ---------------------------------------------------------------------------
extern "C" void kernel_launch(void* const* d_in, const int* in_sizes, int n_in,
                              void* d_out, int out_size, void* d_ws, size_t ws_size,
                              hipStream_t stream)
{
    (void)in_sizes; (void)n_in; (void)out_size;
    const float* feat = (const float*)d_in[1];
    const float* wrpn = (const float*)d_in[3];
    const float* brpn = (const float*)d_in[4];
    const float* wcls = (const float*)d_in[5];
    const float* bcls = (const float*)d_in[6];
    const float* wreg = (const float*)d_in[7];
    const float* breg = (const float*)d_in[8];
    float* out = (float*)d_out;

    // K-split factor by workspace budget. need(ns) = ns*512*2560*4 + 16,252,928.
    int ns = (ws_size >= 58195968) ? 8 : (ws_size >= 37224448) ? 4 : 2;
    int cper = 16 / ns;
    int cperLog = (ns == 2) ? 3 : (ns == 4) ? 2 : 1;
    size_t pkB = (size_t)ns * 512 * 2560 * 4;

    char* ws = (char*)d_ws;
    // Live ranges:
    //   [0,pkB)            pk     k1m..k2a
    //   [pkB,pkB+16.25M)   Xt+W   kprep..k1m; then smalls (k2a+), part
    //                      (k2a..k2b) and rows (k4..k5) share offsets.
    float* pk = (float*)ws;
    unsigned short* Xthi = (unsigned short*)(ws + pkB);
    unsigned short* Xtlo = Xthi + (size_t)52 * 64 * 512;
    unsigned short* Whi  = (unsigned short*)(ws + pkB + 6815744);
    unsigned short* Wlo  = Whi + (size_t)512 * 4608;

    char* sm = ws + pkB;
    float* score = (float*)(sm + 0);             // 90,000
    float* bx1   = (float*)(sm + 90000);
    float* by1   = (float*)(sm + 180000);
    float* bx2   = (float*)(sm + 270000);
    float* by2   = (float*)(sm + 360000);
    u32*   valid = (u32*)  (sm + 450000);        // 90,000
    u64*   key   = (u64*)  (sm + 540000);        // 180,000
    u32*   rankp = (u32*)  (sm + 720000);        // 450,000 (5 chunks)
    float* sS    = (float*)(sm + 1170000);       // 40,000
    float* sx1   = (float*)(sm + 1210000);
    float* sy1   = (float*)(sm + 1250000);
    float* sx2   = (float*)(sm + 1290000);
    float* sy2   = (float*)(sm + 1330000);
    u32*   sInv  = (u32*)  (sm + 1370000);       // 40,960
    u64*   selfw = (u64*)  (sm + 1410960);       // 81,920
    float* part  = (float*)(sm + 1492880);       // 3,600,000 (k2a..k2b)
    u64*   rows  = (u64*)  (sm + 1492880);       // 12,800,000 (k4..k5) -> ends sm+14.29M < 16.25M
    // peak footprint = pkB + 16,252,928 (ns=4 -> 37.2 MB, proven available)

    AnchorBase ab;
    {
        const float scales[3] = {128.f, 256.f, 512.f};
        const float aspect[3] = {0.5f, 1.f, 2.f};
        for (int ai = 0; ai < 3; ++ai) {
            float hr = sqrtf(aspect[ai]);
            float wratio = 1.0f / hr;
            for (int si = 0; si < 3; ++si) {
                float wsz = wratio * scales[si];
                float hsz = hr * scales[si];
                int a = ai * 3 + si;
                ab.b[a * 4 + 0] = rintf(-wsz / 2.0f);
                ab.b[a * 4 + 1] = rintf(-hsz / 2.0f);
                ab.b[a * 4 + 2] = rintf( wsz / 2.0f);
                ab.b[a * 4 + 3] = rintf( hsz / 2.0f);
            }
        }
    }

    kprep    <<<928, 256, 0, stream>>>(feat, wrpn, Xthi, Xtlo, Whi, Wlo);
    k1m      <<<dim3(8, 20, ns), 256, 0, stream>>>(Xthi, Xtlo, Whi, Wlo, pk, cper, cperLog);
    k2a_heads<<<dim3(40, 8), 256, 0, stream>>>(pk, ns, brpn, wcls, wreg, part);
    k2b_decode<<<88, 256, 0, stream>>>(part, bcls, breg, ab, score, bx1, by1, bx2, by2, valid, key);
    k3a_rank <<<dim3(88, 5), 256, 0, stream>>>(key, rankp);
    k3b_gather<<<88, 256, 0, stream>>>(rankp, score, bx1, by1, bx2, by2, valid,
                                       sS, sx1, sy1, sx2, sy2, sInv);
    k4_mat   <<<dim3(40, 20), 256, 0, stream>>>(sx1, sy1, sx2, sy2, rows, selfw);
    k5_scan  <<<1, 64, 0, stream>>>(rows, selfw, sInv, sS, sx1, sy1, sx2, sy2, out);
}

// Round 9
// 462.809 us; speedup vs baseline: 1.4233x; 1.1979x over previous
//
#include <hip/hip_runtime.h>
#include <cmath>
#include <cstdint>
#include <cstddef>

typedef unsigned long long u64;
typedef unsigned int u32;

#define NPX   2500
#define NANCH 22500
#define PRE_TOPK 10000
#define NWORDS 160      // 160*64 = 10240 bits per NMS row

struct AnchorBase { float b[36]; };

typedef __attribute__((ext_vector_type(8))) short bf16x8;
typedef __attribute__((ext_vector_type(4))) float f32x4;

__device__ inline unsigned short f2bf(float f) {
    u32 u = __float_as_uint(f);
    u32 r = u + 0x7fffu + ((u >> 16) & 1u);
    return (unsigned short)(r >> 16);
}
__device__ inline float bf2f(unsigned short h) {
    return __uint_as_float(((u32)h) << 16);
}

// ---------------------------------------------------------------------------
// KPREP: fused input prep (Xt bf16 hi/lo padded grid; W' bf16 hi/lo).
// ---------------------------------------------------------------------------
__global__ __launch_bounds__(256) void kprep(const float* __restrict__ feat,
                                             const float* __restrict__ wr,
                                             unsigned short* __restrict__ xthi,
                                             unsigned short* __restrict__ xtlo,
                                             unsigned short* __restrict__ whi,
                                             unsigned short* __restrict__ wlo)
{
    __shared__ float sh[4608];
    int bid = blockIdx.x;
    int t = threadIdx.x;
    if (bid < 416) {
        float (*tile)[65] = (float(*)[65])sh;
        int gr = bid >> 3;          // grid row 0..51
        int cc = bid & 7;           // c-chunk
        int tx = t & 63, ty = t >> 6;
        int y = gr - 1;
        bool rowok = (gr >= 1) && (gr <= 50);
#pragma unroll
        for (int i = 0; i < 16; ++i) {
            int c = i * 4 + ty;
            tile[c][tx] = (rowok && tx < 50)
                        ? feat[(size_t)(cc * 64 + c) * NPX + y * 50 + tx] : 0.f;
        }
        __syncthreads();
#pragma unroll
        for (int i = 0; i < 16; ++i) {
            int xp = i * 4 + ty;
            int cell = gr * 64 + xp;
            bool ok = rowok && xp >= 1 && xp <= 50;
            float v = ok ? tile[tx][xp - 1] : 0.f;
            unsigned short hi = f2bf(v);
            xthi[(size_t)cell * 512 + cc * 64 + tx] = hi;
            xtlo[(size_t)cell * 512 + cc * 64 + tx] = f2bf(v - bf2f(hi));
        }
    } else {
        int oc = bid - 416;         // 0..511
        for (int j = t; j < 4608; j += 256) sh[j] = wr[(size_t)oc * 4608 + j];
        __syncthreads();
        for (int k = t; k < 4608; k += 256) {
            int c = k & 511, tap = k >> 9;
            float v = sh[c * 9 + tap];
            unsigned short hi = f2bf(v);
            whi[(size_t)oc * 4608 + k] = hi;
            wlo[(size_t)oc * 4608 + k] = f2bf(v - bf2f(hi));
        }
    }
}

// ---------------------------------------------------------------------------
// K1m v6: LDS-staged MFMA GEMM (m97 anatomy). Register double-buffering is
// unreachable from HIP (R5/R7/R8 all compiled at 52-80 VGPR, loads sunk to
// use site -> latency-serial). Instead: cooperative global->LDS tile staging
// once per K-chunk + ds_read_b128 fragments (compiler pipelines lgkmcnt well).
// Block = 128oc x 128px, 4 waves of 64x64 (4x4 MFMA tiles). BK=64 chunk
// = (tap, 64c); LDS 4x16KB = 64KB -> 2 blocks/CU. Grid (4, 20, ns).
// ---------------------------------------------------------------------------
__global__ __launch_bounds__(256) void k1m(const unsigned short* __restrict__ xthi,
                                           const unsigned short* __restrict__ xtlo,
                                           const unsigned short* __restrict__ whi,
                                           const unsigned short* __restrict__ wlo,
                                           float* __restrict__ pk,
                                           int cptLog, int cptm1, int cptMul, int niter)
{
    __shared__ __align__(16) unsigned short Ah[8192];
    __shared__ __align__(16) unsigned short Al[8192];
    __shared__ __align__(16) unsigned short Bh[8192];
    __shared__ __align__(16) unsigned short Bl[8192];

    int t = threadIdx.x;
    int lane = t & 63, wave = t >> 6;
    int wo = wave & 1, wp = wave >> 1;
    int ocb = blockIdx.x, pxb = blockIdx.y, bs = blockIdx.z;
    int q = lane >> 4, m = lane & 15;
    int c0base = bs * cptMul;

    // staging geometry: thread handles granule g (16B) of rows r0+32i
    int g  = t & 7;
    int r0 = t >> 3;
    int cellB[4];
    int ocA[4];
#pragma unroll
    for (int i = 0; i < 4; ++i) {
        int rl = r0 + 32 * i;
        int opx = pxb * 128 + rl;
        cellB[i] = (opx < NPX) ? ((opx / 50) + 1) * 64 + (opx % 50) + 1 : 190;
        ocA[i] = ocb * 128 + rl;
    }

    f32x4 acc[16];
    f32x4 zf = {0.f, 0.f, 0.f, 0.f};
#pragma unroll
    for (int i = 0; i < 16; ++i) acc[i] = zf;

    for (int it = 0; it < niter; ++it) {
        int tap = it >> cptLog;
        int cw  = it & cptm1;
        int c0  = c0base + cw * 64;
        int t3  = (tap * 43) >> 7;                      // tap/3
        int tapoff = (t3 - 1) * 64 + (tap - t3 * 3) - 1;
        // ---- stage 64KB: A(128oc x 64k) + B(128px x 64k), hi+lo ----
#pragma unroll
        for (int i = 0; i < 4; ++i) {
            int rl = r0 + 32 * i;
            int la = rl * 64 + g * 8;
            size_t ga = (size_t)ocA[i] * 4608 + tap * 512 + c0 + g * 8;
            *(bf16x8*)(Ah + la) = *(const bf16x8*)(whi + ga);
            *(bf16x8*)(Al + la) = *(const bf16x8*)(wlo + ga);
            size_t gb = (size_t)(cellB[i] + tapoff) * 512 + c0 + g * 8;
            *(bf16x8*)(Bh + la) = *(const bf16x8*)(xthi + gb);
            *(bf16x8*)(Bl + la) = *(const bf16x8*)(xtlo + gb);
        }
        __syncthreads();
        // ---- compute: 2 k-steps of 32 ----
#pragma unroll
        for (int ks = 0; ks < 2; ++ks) {
            bf16x8 fah[4], fal[4], fbh[4], fbl[4];
#pragma unroll
            for (int mt = 0; mt < 4; ++mt) {
                int off = (wo * 64 + mt * 16 + m) * 64 + ks * 32 + q * 8;
                fah[mt] = *(const bf16x8*)(Ah + off);
                fal[mt] = *(const bf16x8*)(Al + off);
            }
#pragma unroll
            for (int nt = 0; nt < 4; ++nt) {
                int off = (wp * 64 + nt * 16 + m) * 64 + ks * 32 + q * 8;
                fbh[nt] = *(const bf16x8*)(Bh + off);
                fbl[nt] = *(const bf16x8*)(Bl + off);
            }
#pragma unroll
            for (int mt = 0; mt < 4; ++mt)
#pragma unroll
                for (int nt = 0; nt < 4; ++nt) {
                    f32x4 a = acc[mt * 4 + nt];
                    a = __builtin_amdgcn_mfma_f32_16x16x32_bf16(fal[mt], fbh[nt], a, 0, 0, 0);
                    a = __builtin_amdgcn_mfma_f32_16x16x32_bf16(fah[mt], fbl[nt], a, 0, 0, 0);
                    a = __builtin_amdgcn_mfma_f32_16x16x32_bf16(fah[mt], fbh[nt], a, 0, 0, 0);
                    acc[mt * 4 + nt] = a;
                }
        }
        __syncthreads();
    }
    // C/D: col(px)=lane&15, row(oc)=quad*4+reg
#pragma unroll
    for (int mt = 0; mt < 4; ++mt)
#pragma unroll
        for (int nt = 0; nt < 4; ++nt)
#pragma unroll
            for (int r = 0; r < 4; ++r) {
                int oc = ocb * 128 + wo * 64 + mt * 16 + q * 4 + r;
                int px = pxb * 128 + wp * 64 + nt * 16 + m;
                pk[((size_t)bs * 512 + oc) * 2560 + px] = acc[mt * 4 + nt][r];
            }
}

// ---------------------------------------------------------------------------
// K2a: fused k-split reduce + bias + ReLU + 1x1 heads partial GEMM.
// Grid (40 px-tiles, 8 c-chunks) = 320 blocks.
// ---------------------------------------------------------------------------
__global__ __launch_bounds__(256) void k2a_heads(const float* __restrict__ pk, int ns,
                                                 const float* __restrict__ br,
                                                 const float* __restrict__ wcls,
                                                 const float* __restrict__ wreg,
                                                 float* __restrict__ part)
{
    __shared__ float vt[64 * 64];
    __shared__ float Wl[45 * 64];
    int t  = threadIdx.x;
    int pb = blockIdx.x;           // 0..39
    int s  = blockIdx.y;           // 0..7
    int cb = s * 64;
    for (int e = t; e < 45 * 64; e += 256) {
        int u = e >> 6, c = e & 63;
        Wl[e] = (u < 9) ? wcls[u * 512 + cb + c] : wreg[(u - 9) * 512 + cb + c];
    }
    int pxl = t & 63, ug = t >> 6;
    int px = pb * 64 + pxl;
    bool ok = px < NPX;
#pragma unroll
    for (int i = 0; i < 16; ++i) {
        int c = ug * 16 + i;       // wave-uniform
        float v = 0.f;
        if (ok) {
            size_t bidx = (size_t)(cb + c) * 2560 + px;
            v = br[cb + c];
            for (int ks = 0; ks < ns; ++ks) v += pk[(size_t)ks * 512 * 2560 + bidx];
            v = v > 0.f ? v : 0.f;
        }
        vt[c * 64 + pxl] = v;
    }
    __syncthreads();
    int ubase = ug * 12;
    int ulim  = (45 - ubase < 12) ? (45 - ubase) : 12;
    float acc[12];
#pragma unroll
    for (int j = 0; j < 12; ++j) acc[j] = 0.f;
    for (int c = 0; c < 64; ++c) {
        float v = vt[c * 64 + pxl];
#pragma unroll
        for (int j = 0; j < 12; ++j)
            acc[j] = fmaf(v, Wl[(ubase + j) * 64 + c], acc[j]);
    }
    if (ok) {
        for (int j = 0; j < ulim; ++j)
            part[((size_t)s * 45 + ubase + j) * NPX + px] = acc[j];
    }
}

// ---------------------------------------------------------------------------
// K2b: reduce partials + bias, sigmoid, decode, clip, validity, sort key.
// ---------------------------------------------------------------------------
__global__ __launch_bounds__(256) void k2b_decode(const float* __restrict__ part,
                                                  const float* __restrict__ bcls,
                                                  const float* __restrict__ breg,
                                                  AnchorBase ab,
                                                  float* __restrict__ score,
                                                  float* __restrict__ bx1, float* __restrict__ by1,
                                                  float* __restrict__ bx2, float* __restrict__ by2,
                                                  u32* __restrict__ valid,
                                                  u64* __restrict__ key)
{
    int id = blockIdx.x * 256 + threadIdx.x;
    if (id >= NANCH) return;
    int k  = id / NPX;
    int px = id - k * NPX;

    float z  = bcls[k];
    float d0 = breg[k * 4 + 0], d1 = breg[k * 4 + 1];
    float d2 = breg[k * 4 + 2], d3 = breg[k * 4 + 3];
#pragma unroll
    for (int s = 0; s < 8; ++s) {
        const float* p = part + (size_t)s * 45 * NPX;
        z  += p[(size_t)k * NPX + px];
        d0 += p[(size_t)(9 + k * 4 + 0) * NPX + px];
        d1 += p[(size_t)(9 + k * 4 + 1) * NPX + px];
        d2 += p[(size_t)(9 + k * 4 + 2) * NPX + px];
        d3 += p[(size_t)(9 + k * 4 + 3) * NPX + px];
    }
    float sc = 1.f / (1.f + expf(-z));

    int yy = px / 50, xx = px - (px / 50) * 50;
    float fx = (float)xx, fy = (float)yy;
    float ax1 = fx + ab.b[k * 4 + 0], ay1 = fy + ab.b[k * 4 + 1];
    float ax2 = fx + ab.b[k * 4 + 2], ay2 = fy + ab.b[k * 4 + 3];
    float aw = ax2 - ax1, ah = ay2 - ay1;
    float cx = ax1 + 0.5f * aw, cy = ay1 + 0.5f * ah;
    float pcx = d0 * aw + cx, pcy = d1 * ah + cy;
    float pw = expf(d2) * aw, ph = expf(d3) * ah;
    float x1 = pcx - 0.5f * pw, y1 = pcy - 0.5f * ph;
    float x2 = pcx + 0.5f * pw, y2 = pcy + 0.5f * ph;
    x1 = fminf(fmaxf(x1, 0.f), 800.f);
    y1 = fminf(fmaxf(y1, 0.f), 800.f);
    x2 = fminf(fmaxf(x2, 0.f), 800.f);
    y2 = fminf(fmaxf(y2, 0.f), 800.f);
    u32 v = ((x2 - x1) >= 16.f) && ((y2 - y1) >= 16.f);

    int f = px * 9 + k;
    score[f] = sc;
    bx1[f] = x1; by1[f] = y1; bx2[f] = x2; by2[f] = y2;
    valid[f] = v;
    u32 sb = __float_as_uint(sc);
    key[f] = ((u64)(~sb) << 32) | (u32)f;
}

// ---------------------------------------------------------------------------
// K3a: partial ranks, LDS-staged, b128 paired reads.
// ---------------------------------------------------------------------------
__global__ __launch_bounds__(256) void k3a_rank(const u64* __restrict__ key,
                                                u32* __restrict__ rankp)
{
    __shared__ __align__(16) u64 sk[4500];
    int t  = threadIdx.x;
    int jb = blockIdx.y;           // 0..4
    for (int e = t; e < 4500; e += 256) sk[e] = key[jb * 4500 + e];
    __syncthreads();
    int i = blockIdx.x * 256 + t;
    if (i >= NANCH) return;
    u64 ki = key[i];
    const ulonglong2* sk2 = (const ulonglong2*)sk;
    u32 cnt = 0;
#pragma unroll 5
    for (int j = 0; j < 2250; ++j) {
        ulonglong2 v = sk2[j];
        cnt += (v.x < ki) ? 1u : 0u;
        cnt += (v.y < ki) ? 1u : 0u;
    }
    rankp[(size_t)jb * NANCH + i] = cnt;
}

// ---------------------------------------------------------------------------
// K3b: sum 5 partial ranks, scatter top-10000; sInv[r] = 1 if invalid box.
// ---------------------------------------------------------------------------
__global__ __launch_bounds__(256) void k3b_gather(const u32* __restrict__ rankp,
                                                  const float* __restrict__ score,
                                                  const float* __restrict__ bx1, const float* __restrict__ by1,
                                                  const float* __restrict__ bx2, const float* __restrict__ by2,
                                                  const u32* __restrict__ valid,
                                                  float* __restrict__ sS,
                                                  float* __restrict__ sx1, float* __restrict__ sy1,
                                                  float* __restrict__ sx2, float* __restrict__ sy2,
                                                  u32* __restrict__ sInv)
{
    int i = blockIdx.x * 256 + threadIdx.x;
    if (i >= NANCH) return;
    u32 r = rankp[i] + rankp[NANCH + i] + rankp[2 * NANCH + i]
          + rankp[3 * NANCH + i] + rankp[4 * NANCH + i];
    if (r >= PRE_TOPK) return;
    sS[r] = score[i];
    sx1[r] = bx1[i]; sy1[r] = by1[i]; sx2[r] = bx2[i]; sy2[r] = by2[i];
    sInv[r] = valid[i] ? 0u : 1u;
}

// ---------------------------------------------------------------------------
// K4 v3: ballot-transpose suppression matrix (R7 — verified).
// ---------------------------------------------------------------------------
__global__ __launch_bounds__(256) void k4_mat(const float* __restrict__ sx1, const float* __restrict__ sy1,
                                              const float* __restrict__ sx2, const float* __restrict__ sy2,
                                              u64* __restrict__ rows,
                                              u64* __restrict__ selfw)
{
    __shared__ float4 ib4[256];
    __shared__ float  ibA[256];
    int t = threadIdx.x, lane = t & 63, wave = t >> 6;
    int i0 = blockIdx.x * 256;
    int jw0 = blockIdx.y * 8 + wave * 2;      // this wave's 2 words

    {
        int gi = i0 + t;
        float4 b4 = {0.f, 0.f, 0.f, 0.f};
        float a = 0.f;
        if (gi < PRE_TOPK) {
            b4.x = sx1[gi]; b4.y = sy1[gi]; b4.z = sx2[gi]; b4.w = sy2[gi];
            a = (b4.z - b4.x) * (b4.w - b4.y);
        }
        ib4[t] = b4; ibA[t] = a;
    }
    float jx1[2], jy1[2], jx2[2], jy2[2], ja[2];
#pragma unroll
    for (int wsel = 0; wsel < 2; ++wsel) {
        int j = (jw0 + wsel) * 64 + lane;
        float a1 = sx1[j], b1 = sy1[j], a2 = sx2[j], b2 = sy2[j];
        jx1[wsel] = a1; jy1[wsel] = b1; jx2[wsel] = a2; jy2[wsel] = b2;
        ja[wsel] = (a2 - a1) * (b2 - b1);
    }
    __syncthreads();

    int imax = PRE_TOPK - i0;
    if (imax > 256) imax = 256;
    for (int ii = 0; ii < imax; ++ii) {
        int i = i0 + ii;
        u64 msk[2];
#pragma unroll
        for (int wsel = 0; wsel < 2; ++wsel) {
            int jw = jw0 + wsel;
            int lo = jw * 64;
            u64 m = (i < lo) ? ~0ull
                  : ((i - lo >= 63) ? 0ull : ~((2ull << (i - lo)) - 1ull));
            u64 jmask = (jw < 156) ? ~0ull : ((jw == 156) ? 0xFFFFull : 0ull);
            msk[wsel] = m & jmask;
        }
        u64 w0 = 0, w1 = 0;
        if (msk[0] | msk[1]) {
            float4 bi = ib4[ii];          // LDS broadcast
            float ai = ibA[ii];
#pragma unroll
            for (int wsel = 0; wsel < 2; ++wsel) {
                if (!msk[wsel]) continue;
                float xx1 = fmaxf(bi.x, jx1[wsel]);
                float yy1 = fmaxf(bi.y, jy1[wsel]);
                float xx2 = fminf(bi.z, jx2[wsel]);
                float yy2 = fminf(bi.w, jy2[wsel]);
                float iw = fmaxf(xx2 - xx1, 0.f);
                float ih = fmaxf(yy2 - yy1, 0.f);
                float inter = iw * ih;
                float uni = ai + ja[wsel] - inter;
                u64 b = __ballot(inter > 0.7f * uni) & msk[wsel];
                if (wsel == 0) w0 = b; else w1 = b;
            }
        }
        if (lane == 0) {
            rows[(size_t)i * NWORDS + jw0]     = w0;
            rows[(size_t)i * NWORDS + jw0 + 1] = w1;
            int sw = i >> 6;
            if (sw == jw0)     selfw[i] = w0;
            if (sw == jw0 + 1) selfw[i] = w1;
        }
    }
}

// ---------------------------------------------------------------------------
// K5: word-batched greedy NMS scan (batch 16); initial removed bits from sInv;
// zero-fills output tail.
// ---------------------------------------------------------------------------
__global__ __launch_bounds__(64) void k5_scan(const u64* __restrict__ rows,
                                              const u64* __restrict__ selfw,
                                              const u32* __restrict__ sInv,
                                              const float* __restrict__ sS,
                                              const float* __restrict__ sx1, const float* __restrict__ sy1,
                                              const float* __restrict__ sx2, const float* __restrict__ sy2,
                                              float* __restrict__ out)
{
    __shared__ int keptList[2000];
    __shared__ int kcnt;
    int l = threadIdx.x;
    auto bw = [&](int w) -> u64 {
        const uint4* p = (const uint4*)(sInv + (size_t)w * 64);
        u64 v = 0;
#pragma unroll
        for (int j = 0; j < 16; ++j) {
            uint4 q = p[j];
            v |= ((u64)(q.x != 0) << (j * 4))     | ((u64)(q.y != 0) << (j * 4 + 1))
               | ((u64)(q.z != 0) << (j * 4 + 2)) | ((u64)(q.w != 0) << (j * 4 + 3));
        }
        return v;
    };
    u64 r0 = bw(l);
    u64 r1 = bw(64 + l);
    u64 r2 = (l < 32) ? bw(128 + l) : ~0ull;
    u64 swreg = selfw[l];
    int cnt = 0;
    bool done = false;
    for (int w = 0; w < 157 && !done; ++w) {
        u64 swnext = (w < 156) ? selfw[(size_t)(w + 1) * 64 + l] : 0ull;
        int slot = w >> 6, owner = w & 63;
        u64 val = (slot == 0) ? r0 : (slot == 1) ? r1 : r2;
        u64 rw = __shfl(val, owner, 64);
        u64 wmask = (w == 156) ? 0xFFFFull : ~0ull;
        u64 av = (~rw) & wmask;
        u64 km = 0;
        while (av) {                     // intra-word resolve, registers only
            int b = __ffsll((unsigned long long)av) - 1;
            u64 sw = __shfl(swreg, b, 64);
            km |= 1ull << b;
            av &= ~(1ull << b);
            av &= ~sw;
        }
        u64 kk = km;
        while (kk) {                     // OR kept rows, 16 per batch
            int bsx[16];
            int nb = 0;
            while (kk && nb < 16) {
                int b = __ffsll((unsigned long long)kk) - 1;
                kk &= kk - 1;
                bsx[nb++] = b;
            }
            u64 a0 = 0, a1 = 0, a2 = 0;
#pragma unroll
            for (int u = 0; u < 16; ++u) {
                if (u < nb) {
                    int i = (w << 6) + bsx[u];
                    if (l == 0 && cnt + u < 2000) keptList[cnt + u] = i;
                    const u64* rp = rows + (size_t)i * NWORDS;
                    a0 |= rp[l];
                    a1 |= rp[64 + l];
                    if (l < 32) a2 |= rp[128 + l];
                }
            }
            r0 |= a0; r1 |= a1; r2 |= a2;
            cnt += nb;
            if (cnt >= 2000) { done = true; break; }
        }
        swreg = swnext;
    }
    if (l == 0) kcnt = (cnt < 2000) ? cnt : 2000;
    __syncthreads();
    int K = kcnt;
    for (int r = l; r < 2000; r += 64) {
        if (r < K) {
            int j = keptList[r];
            out[r * 4 + 0] = sx1[j];
            out[r * 4 + 1] = sy1[j];
            out[r * 4 + 2] = sx2[j];
            out[r * 4 + 3] = sy2[j];
            out[8000 + r]  = sS[j];
        } else {
            out[r * 4 + 0] = 0.f; out[r * 4 + 1] = 0.f;
            out[r * 4 + 2] = 0.f; out[r * 4 + 3] = 0.f;
            out[8000 + r]  = 0.f;
        }
    }
}

// ---------------------------------------------------------------------------
extern "C" void kernel_launch(void* const* d_in, const int* in_sizes, int n_in,
                              void* d_out, int out_size, void* d_ws, size_t ws_size,
                              hipStream_t stream)
{
    (void)in_sizes; (void)n_in; (void)out_size;
    const float* feat = (const float*)d_in[1];
    const float* wrpn = (const float*)d_in[3];
    const float* brpn = (const float*)d_in[4];
    const float* wcls = (const float*)d_in[5];
    const float* bcls = (const float*)d_in[6];
    const float* wreg = (const float*)d_in[7];
    const float* breg = (const float*)d_in[8];
    float* out = (float*)d_out;

    // K-split factor by workspace budget. need(ns) = ns*512*2560*4 + 16,252,928.
    int ns = (ws_size >= 58195968) ? 8 : (ws_size >= 37224448) ? 4 : 2;
    int cpt     = 8 / ns;                 // 64c-chunks per tap per z-slice
    int cptLog  = (ns == 2) ? 2 : (ns == 4) ? 1 : 0;
    int cptm1   = cpt - 1;
    int cptMul  = cpt * 64;               // c0base = bs * cptMul
    int niter   = 9 * cpt;
    size_t pkB = (size_t)ns * 512 * 2560 * 4;

    char* ws = (char*)d_ws;
    // Live ranges:
    //   [0,pkB)            pk     k1m..k2a
    //   [pkB,pkB+16.25M)   Xt+W   kprep..k1m; then smalls (k2a+), part
    //                      (k2a..k2b) and rows (k4..k5) share offsets.
    float* pk = (float*)ws;
    unsigned short* Xthi = (unsigned short*)(ws + pkB);
    unsigned short* Xtlo = Xthi + (size_t)52 * 64 * 512;
    unsigned short* Whi  = (unsigned short*)(ws + pkB + 6815744);
    unsigned short* Wlo  = Whi + (size_t)512 * 4608;

    char* sm = ws + pkB;
    float* score = (float*)(sm + 0);             // 90,000
    float* bx1   = (float*)(sm + 90000);
    float* by1   = (float*)(sm + 180000);
    float* bx2   = (float*)(sm + 270000);
    float* by2   = (float*)(sm + 360000);
    u32*   valid = (u32*)  (sm + 450000);        // 90,000
    u64*   key   = (u64*)  (sm + 540000);        // 180,000
    u32*   rankp = (u32*)  (sm + 720000);        // 450,000 (5 chunks)
    float* sS    = (float*)(sm + 1170000);       // 40,000
    float* sx1   = (float*)(sm + 1210000);
    float* sy1   = (float*)(sm + 1250000);
    float* sx2   = (float*)(sm + 1290000);
    float* sy2   = (float*)(sm + 1330000);
    u32*   sInv  = (u32*)  (sm + 1370000);       // 40,960
    u64*   selfw = (u64*)  (sm + 1410960);       // 81,920
    float* part  = (float*)(sm + 1492880);       // 3,600,000 (k2a..k2b)
    u64*   rows  = (u64*)  (sm + 1492880);       // 12,800,000 (k4..k5) -> ends sm+14.29M < 16.25M
    // peak footprint = pkB + 16,252,928 (ns=4 -> 37.2 MB, proven available)

    AnchorBase ab;
    {
        const float scales[3] = {128.f, 256.f, 512.f};
        const float aspect[3] = {0.5f, 1.f, 2.f};
        for (int ai = 0; ai < 3; ++ai) {
            float hr = sqrtf(aspect[ai]);
            float wratio = 1.0f / hr;
            for (int si = 0; si < 3; ++si) {
                float wsz = wratio * scales[si];
                float hsz = hr * scales[si];
                int a = ai * 3 + si;
                ab.b[a * 4 + 0] = rintf(-wsz / 2.0f);
                ab.b[a * 4 + 1] = rintf(-hsz / 2.0f);
                ab.b[a * 4 + 2] = rintf( wsz / 2.0f);
                ab.b[a * 4 + 3] = rintf( hsz / 2.0f);
            }
        }
    }

    kprep    <<<928, 256, 0, stream>>>(feat, wrpn, Xthi, Xtlo, Whi, Wlo);
    k1m      <<<dim3(4, 20, ns), 256, 0, stream>>>(Xthi, Xtlo, Whi, Wlo, pk,
                                                   cptLog, cptm1, cptMul, niter);
    k2a_heads<<<dim3(40, 8), 256, 0, stream>>>(pk, ns, brpn, wcls, wreg, part);
    k2b_decode<<<88, 256, 0, stream>>>(part, bcls, breg, ab, score, bx1, by1, bx2, by2, valid, key);
    k3a_rank <<<dim3(88, 5), 256, 0, stream>>>(key, rankp);
    k3b_gather<<<88, 256, 0, stream>>>(rankp, score, bx1, by1, bx2, by2, valid,
                                       sS, sx1, sy1, sx2, sy2, sInv);
    k4_mat   <<<dim3(40, 20), 256, 0, stream>>>(sx1, sy1, sx2, sy2, rows, selfw);
    k5_scan  <<<1, 64, 0, stream>>>(rows, selfw, sInv, sS, sx1, sy1, sx2, sy2, out);
}

// Round 10
// 384.633 us; speedup vs baseline: 1.7126x; 1.2032x over previous
//
#include <hip/hip_runtime.h>
#include <cmath>
#include <cstdint>
#include <cstddef>

typedef unsigned long long u64;
typedef unsigned int u32;

#define NPX   2500
#define NANCH 22500
#define PRE_TOPK 10000
#define NWORDS 160      // 160*64 = 10240 bits per NMS row

struct AnchorBase { float b[36]; };

typedef __attribute__((ext_vector_type(8))) short bf16x8;
typedef __attribute__((ext_vector_type(4))) float f32x4;

__device__ inline unsigned short f2bf(float f) {
    u32 u = __float_as_uint(f);
    u32 r = u + 0x7fffu + ((u >> 16) & 1u);
    return (unsigned short)(r >> 16);
}
__device__ inline float bf2f(unsigned short h) {
    return __uint_as_float(((u32)h) << 16);
}

// ---------------------------------------------------------------------------
// KPREP: fused input prep (Xt bf16 hi/lo padded grid; W' bf16 hi/lo).
// ---------------------------------------------------------------------------
__global__ __launch_bounds__(256) void kprep(const float* __restrict__ feat,
                                             const float* __restrict__ wr,
                                             unsigned short* __restrict__ xthi,
                                             unsigned short* __restrict__ xtlo,
                                             unsigned short* __restrict__ whi,
                                             unsigned short* __restrict__ wlo)
{
    __shared__ float sh[4608];
    int bid = blockIdx.x;
    int t = threadIdx.x;
    if (bid < 416) {
        float (*tile)[65] = (float(*)[65])sh;
        int gr = bid >> 3;          // grid row 0..51
        int cc = bid & 7;           // c-chunk
        int tx = t & 63, ty = t >> 6;
        int y = gr - 1;
        bool rowok = (gr >= 1) && (gr <= 50);
#pragma unroll
        for (int i = 0; i < 16; ++i) {
            int c = i * 4 + ty;
            tile[c][tx] = (rowok && tx < 50)
                        ? feat[(size_t)(cc * 64 + c) * NPX + y * 50 + tx] : 0.f;
        }
        __syncthreads();
#pragma unroll
        for (int i = 0; i < 16; ++i) {
            int xp = i * 4 + ty;
            int cell = gr * 64 + xp;
            bool ok = rowok && xp >= 1 && xp <= 50;
            float v = ok ? tile[tx][xp - 1] : 0.f;
            unsigned short hi = f2bf(v);
            xthi[(size_t)cell * 512 + cc * 64 + tx] = hi;
            xtlo[(size_t)cell * 512 + cc * 64 + tx] = f2bf(v - bf2f(hi));
        }
    } else {
        int oc = bid - 416;         // 0..511
        for (int j = t; j < 4608; j += 256) sh[j] = wr[(size_t)oc * 4608 + j];
        __syncthreads();
        for (int k = t; k < 4608; k += 256) {
            int c = k & 511, tap = k >> 9;
            float v = sh[c * 9 + tap];
            unsigned short hi = f2bf(v);
            whi[(size_t)oc * 4608 + k] = hi;
            wlo[(size_t)oc * 4608 + k] = f2bf(v - bf2f(hi));
        }
    }
}

// ---------------------------------------------------------------------------
// K1m v6: LDS-staged MFMA GEMM (m97 anatomy) — verified R9: the only HIP-
// reachable structure that feeds MFMA (register dbuf is compiler-demoted).
// ---------------------------------------------------------------------------
__global__ __launch_bounds__(256) void k1m(const unsigned short* __restrict__ xthi,
                                           const unsigned short* __restrict__ xtlo,
                                           const unsigned short* __restrict__ whi,
                                           const unsigned short* __restrict__ wlo,
                                           float* __restrict__ pk,
                                           int cptLog, int cptm1, int cptMul, int niter)
{
    __shared__ __align__(16) unsigned short Ah[8192];
    __shared__ __align__(16) unsigned short Al[8192];
    __shared__ __align__(16) unsigned short Bh[8192];
    __shared__ __align__(16) unsigned short Bl[8192];

    int t = threadIdx.x;
    int lane = t & 63, wave = t >> 6;
    int wo = wave & 1, wp = wave >> 1;
    int ocb = blockIdx.x, pxb = blockIdx.y, bs = blockIdx.z;
    int q = lane >> 4, m = lane & 15;
    int c0base = bs * cptMul;

    int g  = t & 7;
    int r0 = t >> 3;
    int cellB[4];
    int ocA[4];
#pragma unroll
    for (int i = 0; i < 4; ++i) {
        int rl = r0 + 32 * i;
        int opx = pxb * 128 + rl;
        cellB[i] = (opx < NPX) ? ((opx / 50) + 1) * 64 + (opx % 50) + 1 : 190;
        ocA[i] = ocb * 128 + rl;
    }

    f32x4 acc[16];
    f32x4 zf = {0.f, 0.f, 0.f, 0.f};
#pragma unroll
    for (int i = 0; i < 16; ++i) acc[i] = zf;

    for (int it = 0; it < niter; ++it) {
        int tap = it >> cptLog;
        int cw  = it & cptm1;
        int c0  = c0base + cw * 64;
        int t3  = (tap * 43) >> 7;                      // tap/3
        int tapoff = (t3 - 1) * 64 + (tap - t3 * 3) - 1;
#pragma unroll
        for (int i = 0; i < 4; ++i) {
            int rl = r0 + 32 * i;
            int la = rl * 64 + g * 8;
            size_t ga = (size_t)ocA[i] * 4608 + tap * 512 + c0 + g * 8;
            *(bf16x8*)(Ah + la) = *(const bf16x8*)(whi + ga);
            *(bf16x8*)(Al + la) = *(const bf16x8*)(wlo + ga);
            size_t gb = (size_t)(cellB[i] + tapoff) * 512 + c0 + g * 8;
            *(bf16x8*)(Bh + la) = *(const bf16x8*)(xthi + gb);
            *(bf16x8*)(Bl + la) = *(const bf16x8*)(xtlo + gb);
        }
        __syncthreads();
#pragma unroll
        for (int ks = 0; ks < 2; ++ks) {
            bf16x8 fah[4], fal[4], fbh[4], fbl[4];
#pragma unroll
            for (int mt = 0; mt < 4; ++mt) {
                int off = (wo * 64 + mt * 16 + m) * 64 + ks * 32 + q * 8;
                fah[mt] = *(const bf16x8*)(Ah + off);
                fal[mt] = *(const bf16x8*)(Al + off);
            }
#pragma unroll
            for (int nt = 0; nt < 4; ++nt) {
                int off = (wp * 64 + nt * 16 + m) * 64 + ks * 32 + q * 8;
                fbh[nt] = *(const bf16x8*)(Bh + off);
                fbl[nt] = *(const bf16x8*)(Bl + off);
            }
#pragma unroll
            for (int mt = 0; mt < 4; ++mt)
#pragma unroll
                for (int nt = 0; nt < 4; ++nt) {
                    f32x4 a = acc[mt * 4 + nt];
                    a = __builtin_amdgcn_mfma_f32_16x16x32_bf16(fal[mt], fbh[nt], a, 0, 0, 0);
                    a = __builtin_amdgcn_mfma_f32_16x16x32_bf16(fah[mt], fbl[nt], a, 0, 0, 0);
                    a = __builtin_amdgcn_mfma_f32_16x16x32_bf16(fah[mt], fbh[nt], a, 0, 0, 0);
                    acc[mt * 4 + nt] = a;
                }
        }
        __syncthreads();
    }
#pragma unroll
    for (int mt = 0; mt < 4; ++mt)
#pragma unroll
        for (int nt = 0; nt < 4; ++nt)
#pragma unroll
            for (int r = 0; r < 4; ++r) {
                int oc = ocb * 128 + wo * 64 + mt * 16 + q * 4 + r;
                int px = pxb * 128 + wp * 64 + nt * 16 + m;
                pk[((size_t)bs * 512 + oc) * 2560 + px] = acc[mt * 4 + nt][r];
            }
}

// ---------------------------------------------------------------------------
// K2a: fused k-split reduce + bias + ReLU + 1x1 heads partial GEMM.
// ---------------------------------------------------------------------------
__global__ __launch_bounds__(256) void k2a_heads(const float* __restrict__ pk, int ns,
                                                 const float* __restrict__ br,
                                                 const float* __restrict__ wcls,
                                                 const float* __restrict__ wreg,
                                                 float* __restrict__ part)
{
    __shared__ float vt[64 * 64];
    __shared__ float Wl[45 * 64];
    int t  = threadIdx.x;
    int pb = blockIdx.x;           // 0..39
    int s  = blockIdx.y;           // 0..7
    int cb = s * 64;
    for (int e = t; e < 45 * 64; e += 256) {
        int u = e >> 6, c = e & 63;
        Wl[e] = (u < 9) ? wcls[u * 512 + cb + c] : wreg[(u - 9) * 512 + cb + c];
    }
    int pxl = t & 63, ug = t >> 6;
    int px = pb * 64 + pxl;
    bool ok = px < NPX;
#pragma unroll
    for (int i = 0; i < 16; ++i) {
        int c = ug * 16 + i;       // wave-uniform
        float v = 0.f;
        if (ok) {
            size_t bidx = (size_t)(cb + c) * 2560 + px;
            v = br[cb + c];
            for (int ks = 0; ks < ns; ++ks) v += pk[(size_t)ks * 512 * 2560 + bidx];
            v = v > 0.f ? v : 0.f;
        }
        vt[c * 64 + pxl] = v;
    }
    __syncthreads();
    int ubase = ug * 12;
    int ulim  = (45 - ubase < 12) ? (45 - ubase) : 12;
    float acc[12];
#pragma unroll
    for (int j = 0; j < 12; ++j) acc[j] = 0.f;
    for (int c = 0; c < 64; ++c) {
        float v = vt[c * 64 + pxl];
#pragma unroll
        for (int j = 0; j < 12; ++j)
            acc[j] = fmaf(v, Wl[(ubase + j) * 64 + c], acc[j]);
    }
    if (ok) {
        for (int j = 0; j < ulim; ++j)
            part[((size_t)s * 45 + ubase + j) * NPX + px] = acc[j];
    }
}

// ---------------------------------------------------------------------------
// K2b: reduce partials + bias, sigmoid, decode, clip, validity, sort key.
// ---------------------------------------------------------------------------
__global__ __launch_bounds__(256) void k2b_decode(const float* __restrict__ part,
                                                  const float* __restrict__ bcls,
                                                  const float* __restrict__ breg,
                                                  AnchorBase ab,
                                                  float* __restrict__ score,
                                                  float* __restrict__ bx1, float* __restrict__ by1,
                                                  float* __restrict__ bx2, float* __restrict__ by2,
                                                  u32* __restrict__ valid,
                                                  u64* __restrict__ key)
{
    int id = blockIdx.x * 256 + threadIdx.x;
    if (id >= NANCH) return;
    int k  = id / NPX;
    int px = id - k * NPX;

    float z  = bcls[k];
    float d0 = breg[k * 4 + 0], d1 = breg[k * 4 + 1];
    float d2 = breg[k * 4 + 2], d3 = breg[k * 4 + 3];
#pragma unroll
    for (int s = 0; s < 8; ++s) {
        const float* p = part + (size_t)s * 45 * NPX;
        z  += p[(size_t)k * NPX + px];
        d0 += p[(size_t)(9 + k * 4 + 0) * NPX + px];
        d1 += p[(size_t)(9 + k * 4 + 1) * NPX + px];
        d2 += p[(size_t)(9 + k * 4 + 2) * NPX + px];
        d3 += p[(size_t)(9 + k * 4 + 3) * NPX + px];
    }
    float sc = 1.f / (1.f + expf(-z));

    int yy = px / 50, xx = px - (px / 50) * 50;
    float fx = (float)xx, fy = (float)yy;
    float ax1 = fx + ab.b[k * 4 + 0], ay1 = fy + ab.b[k * 4 + 1];
    float ax2 = fx + ab.b[k * 4 + 2], ay2 = fy + ab.b[k * 4 + 3];
    float aw = ax2 - ax1, ah = ay2 - ay1;
    float cx = ax1 + 0.5f * aw, cy = ay1 + 0.5f * ah;
    float pcx = d0 * aw + cx, pcy = d1 * ah + cy;
    float pw = expf(d2) * aw, ph = expf(d3) * ah;
    float x1 = pcx - 0.5f * pw, y1 = pcy - 0.5f * ph;
    float x2 = pcx + 0.5f * pw, y2 = pcy + 0.5f * ph;
    x1 = fminf(fmaxf(x1, 0.f), 800.f);
    y1 = fminf(fmaxf(y1, 0.f), 800.f);
    x2 = fminf(fmaxf(x2, 0.f), 800.f);
    y2 = fminf(fmaxf(y2, 0.f), 800.f);
    u32 v = ((x2 - x1) >= 16.f) && ((y2 - y1) >= 16.f);

    int f = px * 9 + k;
    score[f] = sc;
    bx1[f] = x1; by1[f] = y1; bx2[f] = x2; by2[f] = y2;
    valid[f] = v;
    u32 sb = __float_as_uint(sc);
    key[f] = ((u64)(~sb) << 32) | (u32)f;
}

// ---------------------------------------------------------------------------
// K3a v3: partial ranks, 4-way i-register-blocking (each staged j-key serves
// 4 i-comparisons -> DS-pipe traffic /4; R9's version was DS-bound ~70us).
// Grid (22 i-blocks of 1024, 10 j-chunks of 2250).
// ---------------------------------------------------------------------------
__global__ __launch_bounds__(256) void k3a_rank(const u64* __restrict__ key,
                                                u32* __restrict__ rankp)
{
    __shared__ __align__(16) u64 sk[2250];
    int t  = threadIdx.x;
    int jb = blockIdx.y;           // 0..9
    for (int e = t; e < 2250; e += 256) sk[e] = key[jb * 2250 + e];
    __syncthreads();
    int i0 = blockIdx.x * 1024 + t;
    int i1 = i0 + 256, i2 = i0 + 512, i3 = i0 + 768;
    u64 k0 = (i0 < NANCH) ? key[i0] : 0ull;
    u64 k1 = (i1 < NANCH) ? key[i1] : 0ull;
    u64 k2 = (i2 < NANCH) ? key[i2] : 0ull;
    u64 k3 = (i3 < NANCH) ? key[i3] : 0ull;
    u32 c0 = 0, c1 = 0, c2 = 0, c3 = 0;
    const ulonglong2* sk2 = (const ulonglong2*)sk;
#pragma unroll 5
    for (int j = 0; j < 1125; ++j) {
        ulonglong2 v = sk2[j];
        c0 += (v.x < k0) ? 1u : 0u;  c0 += (v.y < k0) ? 1u : 0u;
        c1 += (v.x < k1) ? 1u : 0u;  c1 += (v.y < k1) ? 1u : 0u;
        c2 += (v.x < k2) ? 1u : 0u;  c2 += (v.y < k2) ? 1u : 0u;
        c3 += (v.x < k3) ? 1u : 0u;  c3 += (v.y < k3) ? 1u : 0u;
    }
    size_t base = (size_t)jb * NANCH;
    if (i0 < NANCH) rankp[base + i0] = c0;
    if (i1 < NANCH) rankp[base + i1] = c1;
    if (i2 < NANCH) rankp[base + i2] = c2;
    if (i3 < NANCH) rankp[base + i3] = c3;
}

// ---------------------------------------------------------------------------
// K3b: sum 10 partial ranks, scatter top-10000 (+ packed float4 boxes for
// k4's vectorized j-loads); sInv[r] = 1 if invalid box.
// ---------------------------------------------------------------------------
__global__ __launch_bounds__(256) void k3b_gather(const u32* __restrict__ rankp,
                                                  const float* __restrict__ score,
                                                  const float* __restrict__ bx1, const float* __restrict__ by1,
                                                  const float* __restrict__ bx2, const float* __restrict__ by2,
                                                  const u32* __restrict__ valid,
                                                  float* __restrict__ sS,
                                                  float* __restrict__ sx1, float* __restrict__ sy1,
                                                  float* __restrict__ sx2, float* __restrict__ sy2,
                                                  float4* __restrict__ sbox4,
                                                  u32* __restrict__ sInv)
{
    int i = blockIdx.x * 256 + threadIdx.x;
    if (i >= NANCH) return;
    u32 r = 0;
#pragma unroll
    for (int c = 0; c < 10; ++c) r += rankp[(size_t)c * NANCH + i];
    if (r >= PRE_TOPK) return;
    float x1 = bx1[i], y1 = by1[i], x2 = bx2[i], y2 = by2[i];
    sS[r] = score[i];
    sx1[r] = x1; sy1[r] = y1; sx2[r] = x2; sy2[r] = y2;
    float4 b4; b4.x = x1; b4.y = y1; b4.z = x2; b4.w = y2;
    sbox4[r] = b4;
    sInv[r] = valid[i] ? 0u : 1u;
}

// ---------------------------------------------------------------------------
// K4 v4: row-per-wave suppression matrix. One wave per box i (i-box in
// registers); lanes = j; loop starts at the DIAGONAL word (triangular work
// vanishes, no per-i mask algebra); one float4 load per j-word; one __ballot
// emits the 64-bit row word. Sub-diagonal words pre-zeroed by memset.
// R7 version cost 131us on mask overhead + dead sub-diagonal blocks.
// ---------------------------------------------------------------------------
__global__ __launch_bounds__(256) void k4_mat(const float4* __restrict__ sbox4,
                                              u64* __restrict__ rows,
                                              u64* __restrict__ selfw)
{
    int t = threadIdx.x, lane = t & 63, wave = t >> 6;
    int i = blockIdx.x * 4 + wave;
    if (i >= PRE_TOPK) return;
    float4 bi = sbox4[i];                       // wave-uniform, loaded once
    float ai = (bi.z - bi.x) * (bi.w - bi.y);
    int wd  = i >> 6;
    int ish = i & 63;
    u64 diagmask = ~((2ull << ish) - 1ull);     // ish=63 -> 0 (no j>i in word)
    u64* rowp = rows + (size_t)i * NWORDS;
    for (int w = wd; w < 157; ++w) {
        float4 bj = sbox4[(w << 6) + lane];     // coalesced dwordx4
        float xx1 = fmaxf(bi.x, bj.x);
        float yy1 = fmaxf(bi.y, bj.y);
        float xx2 = fminf(bi.z, bj.z);
        float yy2 = fminf(bi.w, bj.w);
        float iw = fmaxf(xx2 - xx1, 0.f);
        float ih = fmaxf(yy2 - yy1, 0.f);
        float inter = iw * ih;
        float aj = (bj.z - bj.x) * (bj.w - bj.y);
        float uni = ai + aj - inter;
        u64 b = __ballot(inter > 0.7f * uni);
        if (w == wd)  b &= diagmask;
        if (w == 156) b &= 0xFFFFull;
        if (lane == 0) {
            rowp[w] = b;
            if (w == wd) selfw[i] = b;
        }
    }
}

// ---------------------------------------------------------------------------
// K5: word-batched greedy NMS scan (batch 16); initial removed bits from sInv;
// zero-fills output tail.
// ---------------------------------------------------------------------------
__global__ __launch_bounds__(64) void k5_scan(const u64* __restrict__ rows,
                                              const u64* __restrict__ selfw,
                                              const u32* __restrict__ sInv,
                                              const float* __restrict__ sS,
                                              const float* __restrict__ sx1, const float* __restrict__ sy1,
                                              const float* __restrict__ sx2, const float* __restrict__ sy2,
                                              float* __restrict__ out)
{
    __shared__ int keptList[2000];
    __shared__ int kcnt;
    int l = threadIdx.x;
    auto bw = [&](int w) -> u64 {
        const uint4* p = (const uint4*)(sInv + (size_t)w * 64);
        u64 v = 0;
#pragma unroll
        for (int j = 0; j < 16; ++j) {
            uint4 q = p[j];
            v |= ((u64)(q.x != 0) << (j * 4))     | ((u64)(q.y != 0) << (j * 4 + 1))
               | ((u64)(q.z != 0) << (j * 4 + 2)) | ((u64)(q.w != 0) << (j * 4 + 3));
        }
        return v;
    };
    u64 r0 = bw(l);
    u64 r1 = bw(64 + l);
    u64 r2 = (l < 32) ? bw(128 + l) : ~0ull;
    u64 swreg = selfw[l];
    int cnt = 0;
    bool done = false;
    for (int w = 0; w < 157 && !done; ++w) {
        u64 swnext = (w < 156) ? selfw[(size_t)(w + 1) * 64 + l] : 0ull;
        int slot = w >> 6, owner = w & 63;
        u64 val = (slot == 0) ? r0 : (slot == 1) ? r1 : r2;
        u64 rw = __shfl(val, owner, 64);
        u64 wmask = (w == 156) ? 0xFFFFull : ~0ull;
        u64 av = (~rw) & wmask;
        u64 km = 0;
        while (av) {                     // intra-word resolve, registers only
            int b = __ffsll((unsigned long long)av) - 1;
            u64 sw = __shfl(swreg, b, 64);
            km |= 1ull << b;
            av &= ~(1ull << b);
            av &= ~sw;
        }
        u64 kk = km;
        while (kk) {                     // OR kept rows, 16 per batch
            int bsx[16];
            int nb = 0;
            while (kk && nb < 16) {
                int b = __ffsll((unsigned long long)kk) - 1;
                kk &= kk - 1;
                bsx[nb++] = b;
            }
            u64 a0 = 0, a1 = 0, a2 = 0;
#pragma unroll
            for (int u = 0; u < 16; ++u) {
                if (u < nb) {
                    int i = (w << 6) + bsx[u];
                    if (l == 0 && cnt + u < 2000) keptList[cnt + u] = i;
                    const u64* rp = rows + (size_t)i * NWORDS;
                    a0 |= rp[l];
                    a1 |= rp[64 + l];
                    if (l < 32) a2 |= rp[128 + l];
                }
            }
            r0 |= a0; r1 |= a1; r2 |= a2;
            cnt += nb;
            if (cnt >= 2000) { done = true; break; }
        }
        swreg = swnext;
    }
    if (l == 0) kcnt = (cnt < 2000) ? cnt : 2000;
    __syncthreads();
    int K = kcnt;
    for (int r = l; r < 2000; r += 64) {
        if (r < K) {
            int j = keptList[r];
            out[r * 4 + 0] = sx1[j];
            out[r * 4 + 1] = sy1[j];
            out[r * 4 + 2] = sx2[j];
            out[r * 4 + 3] = sy2[j];
            out[8000 + r]  = sS[j];
        } else {
            out[r * 4 + 0] = 0.f; out[r * 4 + 1] = 0.f;
            out[r * 4 + 2] = 0.f; out[r * 4 + 3] = 0.f;
            out[8000 + r]  = 0.f;
        }
    }
}

// ---------------------------------------------------------------------------
extern "C" void kernel_launch(void* const* d_in, const int* in_sizes, int n_in,
                              void* d_out, int out_size, void* d_ws, size_t ws_size,
                              hipStream_t stream)
{
    (void)in_sizes; (void)n_in; (void)out_size;
    const float* feat = (const float*)d_in[1];
    const float* wrpn = (const float*)d_in[3];
    const float* brpn = (const float*)d_in[4];
    const float* wcls = (const float*)d_in[5];
    const float* bcls = (const float*)d_in[6];
    const float* wreg = (const float*)d_in[7];
    const float* breg = (const float*)d_in[8];
    float* out = (float*)d_out;

    // K-split factor by workspace budget. need(ns) = ns*512*2560*4 + 16,252,928.
    int ns = (ws_size >= 58195968) ? 8 : (ws_size >= 37224448) ? 4 : 2;
    int cpt     = 8 / ns;                 // 64c-chunks per tap per z-slice
    int cptLog  = (ns == 2) ? 2 : (ns == 4) ? 1 : 0;
    int cptm1   = cpt - 1;
    int cptMul  = cpt * 64;               // c0base = bs * cptMul
    int niter   = 9 * cpt;
    size_t pkB = (size_t)ns * 512 * 2560 * 4;

    char* ws = (char*)d_ws;
    // Live ranges:
    //   [0,pkB)            pk     k1m..k2a
    //   [pkB,pkB+16.25M)   Xt+W   kprep..k1m; then smalls (k2a+), part
    //                      (k2a..k2b) and rows (memset/k4..k5) share offsets.
    float* pk = (float*)ws;
    unsigned short* Xthi = (unsigned short*)(ws + pkB);
    unsigned short* Xtlo = Xthi + (size_t)52 * 64 * 512;
    unsigned short* Whi  = (unsigned short*)(ws + pkB + 6815744);
    unsigned short* Wlo  = Whi + (size_t)512 * 4608;

    char* sm = ws + pkB;
    float* score = (float*)(sm + 0);             // 90,000
    float* bx1   = (float*)(sm + 90000);
    float* by1   = (float*)(sm + 180000);
    float* bx2   = (float*)(sm + 270000);
    float* by2   = (float*)(sm + 360000);
    u32*   valid = (u32*)  (sm + 450000);        // 90,000
    u64*   key   = (u64*)  (sm + 540000);        // 180,000
    u32*   rankp = (u32*)  (sm + 720000);        // 900,000 (10 chunks)
    float* sS    = (float*)(sm + 1620000);       // 40,000
    float* sx1   = (float*)(sm + 1660000);
    float* sy1   = (float*)(sm + 1700000);
    float* sx2   = (float*)(sm + 1740000);
    float* sy2   = (float*)(sm + 1780000);
    u32*   sInv  = (u32*)  (sm + 1820000);       // 40,960
    u64*   selfw = (u64*)  (sm + 1860960);       // 81,920
    float4* sbox4= (float4*)(sm + 1942880);      // 163,840 (10240 entries)
    float* part  = (float*)(sm + 2106720);       // 3,600,000 (k2a..k2b)
    u64*   rows  = (u64*)  (sm + 2106720);       // 12,800,000 (k4..k5) -> ends sm+14.91M < 16.25M
    // peak footprint = pkB + 16,252,928 (ns=4 -> 37.2 MB, proven available)

    AnchorBase ab;
    {
        const float scales[3] = {128.f, 256.f, 512.f};
        const float aspect[3] = {0.5f, 1.f, 2.f};
        for (int ai = 0; ai < 3; ++ai) {
            float hr = sqrtf(aspect[ai]);
            float wratio = 1.0f / hr;
            for (int si = 0; si < 3; ++si) {
                float wsz = wratio * scales[si];
                float hsz = hr * scales[si];
                int a = ai * 3 + si;
                ab.b[a * 4 + 0] = rintf(-wsz / 2.0f);
                ab.b[a * 4 + 1] = rintf(-hsz / 2.0f);
                ab.b[a * 4 + 2] = rintf( wsz / 2.0f);
                ab.b[a * 4 + 3] = rintf( hsz / 2.0f);
            }
        }
    }

    kprep    <<<928, 256, 0, stream>>>(feat, wrpn, Xthi, Xtlo, Whi, Wlo);
    k1m      <<<dim3(4, 20, ns), 256, 0, stream>>>(Xthi, Xtlo, Whi, Wlo, pk,
                                                   cptLog, cptm1, cptMul, niter);
    k2a_heads<<<dim3(40, 8), 256, 0, stream>>>(pk, ns, brpn, wcls, wreg, part);
    k2b_decode<<<88, 256, 0, stream>>>(part, bcls, breg, ab, score, bx1, by1, bx2, by2, valid, key);
    k3a_rank <<<dim3(22, 10), 256, 0, stream>>>(key, rankp);
    k3b_gather<<<88, 256, 0, stream>>>(rankp, score, bx1, by1, bx2, by2, valid,
                                       sS, sx1, sy1, sx2, sy2, sbox4, sInv);
    hipMemsetAsync(rows, 0, (size_t)PRE_TOPK * NWORDS * 8, stream);   // sub-diagonal + tail words
    k4_mat   <<<2500, 256, 0, stream>>>(sbox4, rows, selfw);
    k5_scan  <<<1, 64, 0, stream>>>(rows, selfw, sInv, sS, sx1, sy1, sx2, sy2, out);
}

// Round 11
// 371.696 us; speedup vs baseline: 1.7722x; 1.0348x over previous
//
#include <hip/hip_runtime.h>
#include <cmath>
#include <cstdint>
#include <cstddef>

typedef unsigned long long u64;
typedef unsigned int u32;

#define NPX   2500
#define NANCH 22500
#define PRE_TOPK 10000
#define NWORDS 160      // 160*64 = 10240 bits per NMS row

struct AnchorBase { float b[36]; };

typedef __attribute__((ext_vector_type(8))) short bf16x8;
typedef __attribute__((ext_vector_type(4))) float f32x4;

__device__ inline unsigned short f2bf(float f) {
    u32 u = __float_as_uint(f);
    u32 r = u + 0x7fffu + ((u >> 16) & 1u);
    return (unsigned short)(r >> 16);
}
__device__ inline float bf2f(unsigned short h) {
    return __uint_as_float(((u32)h) << 16);
}

// ---------------------------------------------------------------------------
// KPREP: fused input prep (Xt bf16 hi/lo padded grid; W' bf16 hi/lo).
// ---------------------------------------------------------------------------
__global__ __launch_bounds__(256) void kprep(const float* __restrict__ feat,
                                             const float* __restrict__ wr,
                                             unsigned short* __restrict__ xthi,
                                             unsigned short* __restrict__ xtlo,
                                             unsigned short* __restrict__ whi,
                                             unsigned short* __restrict__ wlo)
{
    __shared__ float sh[4608];
    int bid = blockIdx.x;
    int t = threadIdx.x;
    if (bid < 416) {
        float (*tile)[65] = (float(*)[65])sh;
        int gr = bid >> 3;          // grid row 0..51
        int cc = bid & 7;           // c-chunk
        int tx = t & 63, ty = t >> 6;
        int y = gr - 1;
        bool rowok = (gr >= 1) && (gr <= 50);
#pragma unroll
        for (int i = 0; i < 16; ++i) {
            int c = i * 4 + ty;
            tile[c][tx] = (rowok && tx < 50)
                        ? feat[(size_t)(cc * 64 + c) * NPX + y * 50 + tx] : 0.f;
        }
        __syncthreads();
#pragma unroll
        for (int i = 0; i < 16; ++i) {
            int xp = i * 4 + ty;
            int cell = gr * 64 + xp;
            bool ok = rowok && xp >= 1 && xp <= 50;
            float v = ok ? tile[tx][xp - 1] : 0.f;
            unsigned short hi = f2bf(v);
            xthi[(size_t)cell * 512 + cc * 64 + tx] = hi;
            xtlo[(size_t)cell * 512 + cc * 64 + tx] = f2bf(v - bf2f(hi));
        }
    } else {
        int oc = bid - 416;         // 0..511
        for (int j = t; j < 4608; j += 256) sh[j] = wr[(size_t)oc * 4608 + j];
        __syncthreads();
        for (int k = t; k < 4608; k += 256) {
            int c = k & 511, tap = k >> 9;
            float v = sh[c * 9 + tap];
            unsigned short hi = f2bf(v);
            whi[(size_t)oc * 4608 + k] = hi;
            wlo[(size_t)oc * 4608 + k] = f2bf(v - bf2f(hi));
        }
    }
}

// ---------------------------------------------------------------------------
// K1m v7: LDS-staged MFMA GEMM, re-tiled for occupancy. R9's 128x128 blocks
// (64KB LDS, 320 blocks) capped at 2 blocks/CU with a 2:1 tail imbalance.
// v7: block = 128oc x 64px, 48KB LDS -> 3 blocks/CU, 640 blocks (1.5 imbal).
// Wave = 64oc x 32px (4x2 16x16 tiles). Same K-order as R9 (absmax 0.5).
// ---------------------------------------------------------------------------
__global__ __launch_bounds__(256) void k1m(const unsigned short* __restrict__ xthi,
                                           const unsigned short* __restrict__ xtlo,
                                           const unsigned short* __restrict__ whi,
                                           const unsigned short* __restrict__ wlo,
                                           float* __restrict__ pk,
                                           int cptLog, int cptm1, int cptMul, int niter)
{
    __shared__ __align__(16) unsigned short Ah[8192];   // 128oc x 64k
    __shared__ __align__(16) unsigned short Al[8192];
    __shared__ __align__(16) unsigned short Bh[4096];   // 64px x 64k
    __shared__ __align__(16) unsigned short Bl[4096];

    int t = threadIdx.x;
    int lane = t & 63, wave = t >> 6;
    int wo = wave & 1, wp = wave >> 1;   // wo: 64-oc half, wp: 32-px half
    int ocb = blockIdx.x, pxb = blockIdx.y, bs = blockIdx.z;
    int q = lane >> 4, m = lane & 15;
    int c0base = bs * cptMul;

    // staging geometry: thread -> granule g (16B) of row r0 (+32i)
    int g  = t & 7;
    int r0 = t >> 3;                     // 0..31
    int ocA[4];
    int cellB[2];
#pragma unroll
    for (int i = 0; i < 4; ++i) ocA[i] = ocb * 128 + r0 + 32 * i;
#pragma unroll
    for (int i = 0; i < 2; ++i) {
        int opx = pxb * 64 + r0 + 32 * i;
        cellB[i] = (opx < NPX) ? ((opx / 50) + 1) * 64 + (opx % 50) + 1 : 190;
    }

    f32x4 acc[8];
    f32x4 zf = {0.f, 0.f, 0.f, 0.f};
#pragma unroll
    for (int i = 0; i < 8; ++i) acc[i] = zf;

    for (int it = 0; it < niter; ++it) {
        int tap = it >> cptLog;
        int cw  = it & cptm1;
        int c0  = c0base + cw * 64;
        int t3  = (tap * 43) >> 7;                      // tap/3
        int tapoff = (t3 - 1) * 64 + (tap - t3 * 3) - 1;
        // ---- stage 48KB ----
#pragma unroll
        for (int i = 0; i < 4; ++i) {
            int rl = r0 + 32 * i;
            int la = rl * 64 + g * 8;
            size_t ga = (size_t)ocA[i] * 4608 + tap * 512 + c0 + g * 8;
            *(bf16x8*)(Ah + la) = *(const bf16x8*)(whi + ga);
            *(bf16x8*)(Al + la) = *(const bf16x8*)(wlo + ga);
        }
#pragma unroll
        for (int i = 0; i < 2; ++i) {
            int rl = r0 + 32 * i;
            int la = rl * 64 + g * 8;
            size_t gb = (size_t)(cellB[i] + tapoff) * 512 + c0 + g * 8;
            *(bf16x8*)(Bh + la) = *(const bf16x8*)(xthi + gb);
            *(bf16x8*)(Bl + la) = *(const bf16x8*)(xtlo + gb);
        }
        __syncthreads();
        // ---- compute: 2 k-steps of 32 ----
#pragma unroll
        for (int ks = 0; ks < 2; ++ks) {
            bf16x8 fah[4], fal[4], fbh[2], fbl[2];
#pragma unroll
            for (int mt = 0; mt < 4; ++mt) {
                int off = (wo * 64 + mt * 16 + m) * 64 + ks * 32 + q * 8;
                fah[mt] = *(const bf16x8*)(Ah + off);
                fal[mt] = *(const bf16x8*)(Al + off);
            }
#pragma unroll
            for (int nt = 0; nt < 2; ++nt) {
                int off = (wp * 32 + nt * 16 + m) * 64 + ks * 32 + q * 8;
                fbh[nt] = *(const bf16x8*)(Bh + off);
                fbl[nt] = *(const bf16x8*)(Bl + off);
            }
#pragma unroll
            for (int mt = 0; mt < 4; ++mt)
#pragma unroll
                for (int nt = 0; nt < 2; ++nt) {
                    f32x4 a = acc[mt * 2 + nt];
                    a = __builtin_amdgcn_mfma_f32_16x16x32_bf16(fal[mt], fbh[nt], a, 0, 0, 0);
                    a = __builtin_amdgcn_mfma_f32_16x16x32_bf16(fah[mt], fbl[nt], a, 0, 0, 0);
                    a = __builtin_amdgcn_mfma_f32_16x16x32_bf16(fah[mt], fbh[nt], a, 0, 0, 0);
                    acc[mt * 2 + nt] = a;
                }
        }
        __syncthreads();
    }
    // C/D: col(px)=lane&15, row(oc)=quad*4+reg
#pragma unroll
    for (int mt = 0; mt < 4; ++mt)
#pragma unroll
        for (int nt = 0; nt < 2; ++nt)
#pragma unroll
            for (int r = 0; r < 4; ++r) {
                int oc = ocb * 128 + wo * 64 + mt * 16 + q * 4 + r;
                int px = pxb * 64 + wp * 32 + nt * 16 + m;
                pk[((size_t)bs * 512 + oc) * 2560 + px] = acc[mt * 2 + nt][r];
            }
}

// ---------------------------------------------------------------------------
// K2a: fused k-split reduce + bias + ReLU + 1x1 heads partial GEMM.
// ---------------------------------------------------------------------------
__global__ __launch_bounds__(256) void k2a_heads(const float* __restrict__ pk, int ns,
                                                 const float* __restrict__ br,
                                                 const float* __restrict__ wcls,
                                                 const float* __restrict__ wreg,
                                                 float* __restrict__ part)
{
    __shared__ float vt[64 * 64];
    __shared__ float Wl[45 * 64];
    int t  = threadIdx.x;
    int pb = blockIdx.x;           // 0..39
    int s  = blockIdx.y;           // 0..7
    int cb = s * 64;
    for (int e = t; e < 45 * 64; e += 256) {
        int u = e >> 6, c = e & 63;
        Wl[e] = (u < 9) ? wcls[u * 512 + cb + c] : wreg[(u - 9) * 512 + cb + c];
    }
    int pxl = t & 63, ug = t >> 6;
    int px = pb * 64 + pxl;
    bool ok = px < NPX;
#pragma unroll
    for (int i = 0; i < 16; ++i) {
        int c = ug * 16 + i;       // wave-uniform
        float v = 0.f;
        if (ok) {
            size_t bidx = (size_t)(cb + c) * 2560 + px;
            v = br[cb + c];
            for (int ks = 0; ks < ns; ++ks) v += pk[(size_t)ks * 512 * 2560 + bidx];
            v = v > 0.f ? v : 0.f;
        }
        vt[c * 64 + pxl] = v;
    }
    __syncthreads();
    int ubase = ug * 12;
    int ulim  = (45 - ubase < 12) ? (45 - ubase) : 12;
    float acc[12];
#pragma unroll
    for (int j = 0; j < 12; ++j) acc[j] = 0.f;
    for (int c = 0; c < 64; ++c) {
        float v = vt[c * 64 + pxl];
#pragma unroll
        for (int j = 0; j < 12; ++j)
            acc[j] = fmaf(v, Wl[(ubase + j) * 64 + c], acc[j]);
    }
    if (ok) {
        for (int j = 0; j < ulim; ++j)
            part[((size_t)s * 45 + ubase + j) * NPX + px] = acc[j];
    }
}

// ---------------------------------------------------------------------------
// K2b: reduce partials + bias, sigmoid, decode, clip, validity, sort key.
// ---------------------------------------------------------------------------
__global__ __launch_bounds__(256) void k2b_decode(const float* __restrict__ part,
                                                  const float* __restrict__ bcls,
                                                  const float* __restrict__ breg,
                                                  AnchorBase ab,
                                                  float* __restrict__ score,
                                                  float* __restrict__ bx1, float* __restrict__ by1,
                                                  float* __restrict__ bx2, float* __restrict__ by2,
                                                  u32* __restrict__ valid,
                                                  u64* __restrict__ key)
{
    int id = blockIdx.x * 256 + threadIdx.x;
    if (id >= NANCH) return;
    int k  = id / NPX;
    int px = id - k * NPX;

    float z  = bcls[k];
    float d0 = breg[k * 4 + 0], d1 = breg[k * 4 + 1];
    float d2 = breg[k * 4 + 2], d3 = breg[k * 4 + 3];
#pragma unroll
    for (int s = 0; s < 8; ++s) {
        const float* p = part + (size_t)s * 45 * NPX;
        z  += p[(size_t)k * NPX + px];
        d0 += p[(size_t)(9 + k * 4 + 0) * NPX + px];
        d1 += p[(size_t)(9 + k * 4 + 1) * NPX + px];
        d2 += p[(size_t)(9 + k * 4 + 2) * NPX + px];
        d3 += p[(size_t)(9 + k * 4 + 3) * NPX + px];
    }
    float sc = 1.f / (1.f + expf(-z));

    int yy = px / 50, xx = px - (px / 50) * 50;
    float fx = (float)xx, fy = (float)yy;
    float ax1 = fx + ab.b[k * 4 + 0], ay1 = fy + ab.b[k * 4 + 1];
    float ax2 = fx + ab.b[k * 4 + 2], ay2 = fy + ab.b[k * 4 + 3];
    float aw = ax2 - ax1, ah = ay2 - ay1;
    float cx = ax1 + 0.5f * aw, cy = ay1 + 0.5f * ah;
    float pcx = d0 * aw + cx, pcy = d1 * ah + cy;
    float pw = expf(d2) * aw, ph = expf(d3) * ah;
    float x1 = pcx - 0.5f * pw, y1 = pcy - 0.5f * ph;
    float x2 = pcx + 0.5f * pw, y2 = pcy + 0.5f * ph;
    x1 = fminf(fmaxf(x1, 0.f), 800.f);
    y1 = fminf(fmaxf(y1, 0.f), 800.f);
    x2 = fminf(fmaxf(x2, 0.f), 800.f);
    y2 = fminf(fmaxf(y2, 0.f), 800.f);
    u32 v = ((x2 - x1) >= 16.f) && ((y2 - y1) >= 16.f);

    int f = px * 9 + k;
    score[f] = sc;
    bx1[f] = x1; by1[f] = y1; bx2[f] = x2; by2[f] = y2;
    valid[f] = v;
    u32 sb = __float_as_uint(sc);
    key[f] = ((u64)(~sb) << 32) | (u32)f;
}

// ---------------------------------------------------------------------------
// K3a v3: partial ranks, 4-way i-register-blocking (R10 — verified).
// ---------------------------------------------------------------------------
__global__ __launch_bounds__(256) void k3a_rank(const u64* __restrict__ key,
                                                u32* __restrict__ rankp)
{
    __shared__ __align__(16) u64 sk[2250];
    int t  = threadIdx.x;
    int jb = blockIdx.y;           // 0..9
    for (int e = t; e < 2250; e += 256) sk[e] = key[jb * 2250 + e];
    __syncthreads();
    int i0 = blockIdx.x * 1024 + t;
    int i1 = i0 + 256, i2 = i0 + 512, i3 = i0 + 768;
    u64 k0 = (i0 < NANCH) ? key[i0] : 0ull;
    u64 k1 = (i1 < NANCH) ? key[i1] : 0ull;
    u64 k2 = (i2 < NANCH) ? key[i2] : 0ull;
    u64 k3 = (i3 < NANCH) ? key[i3] : 0ull;
    u32 c0 = 0, c1 = 0, c2 = 0, c3 = 0;
    const ulonglong2* sk2 = (const ulonglong2*)sk;
#pragma unroll 5
    for (int j = 0; j < 1125; ++j) {
        ulonglong2 v = sk2[j];
        c0 += (v.x < k0) ? 1u : 0u;  c0 += (v.y < k0) ? 1u : 0u;
        c1 += (v.x < k1) ? 1u : 0u;  c1 += (v.y < k1) ? 1u : 0u;
        c2 += (v.x < k2) ? 1u : 0u;  c2 += (v.y < k2) ? 1u : 0u;
        c3 += (v.x < k3) ? 1u : 0u;  c3 += (v.y < k3) ? 1u : 0u;
    }
    size_t base = (size_t)jb * NANCH;
    if (i0 < NANCH) rankp[base + i0] = c0;
    if (i1 < NANCH) rankp[base + i1] = c1;
    if (i2 < NANCH) rankp[base + i2] = c2;
    if (i3 < NANCH) rankp[base + i3] = c3;
}

// ---------------------------------------------------------------------------
// K3b: sum 10 partial ranks, scatter top-10000 (+ packed float4 boxes);
// sInv[r] = 1 if invalid box.
// ---------------------------------------------------------------------------
__global__ __launch_bounds__(256) void k3b_gather(const u32* __restrict__ rankp,
                                                  const float* __restrict__ score,
                                                  const float* __restrict__ bx1, const float* __restrict__ by1,
                                                  const float* __restrict__ bx2, const float* __restrict__ by2,
                                                  const u32* __restrict__ valid,
                                                  float* __restrict__ sS,
                                                  float* __restrict__ sx1, float* __restrict__ sy1,
                                                  float* __restrict__ sx2, float* __restrict__ sy2,
                                                  float4* __restrict__ sbox4,
                                                  u32* __restrict__ sInv)
{
    int i = blockIdx.x * 256 + threadIdx.x;
    if (i >= NANCH) return;
    u32 r = 0;
#pragma unroll
    for (int c = 0; c < 10; ++c) r += rankp[(size_t)c * NANCH + i];
    if (r >= PRE_TOPK) return;
    float x1 = bx1[i], y1 = by1[i], x2 = bx2[i], y2 = by2[i];
    sS[r] = score[i];
    sx1[r] = x1; sy1[r] = y1; sx2[r] = x2; sy2[r] = y2;
    float4 b4; b4.x = x1; b4.y = y1; b4.z = x2; b4.w = y2;
    sbox4[r] = b4;
    sInv[r] = valid[i] ? 0u : 1u;
}

// ---------------------------------------------------------------------------
// K4 v4: row-per-wave suppression matrix (R10 — verified, ~20us).
// ---------------------------------------------------------------------------
__global__ __launch_bounds__(256) void k4_mat(const float4* __restrict__ sbox4,
                                              u64* __restrict__ rows,
                                              u64* __restrict__ selfw)
{
    int t = threadIdx.x, lane = t & 63, wave = t >> 6;
    int i = blockIdx.x * 4 + wave;
    if (i >= PRE_TOPK) return;
    float4 bi = sbox4[i];                       // wave-uniform, loaded once
    float ai = (bi.z - bi.x) * (bi.w - bi.y);
    int wd  = i >> 6;
    int ish = i & 63;
    u64 diagmask = ~((2ull << ish) - 1ull);     // ish=63 -> 0 (no j>i in word)
    u64* rowp = rows + (size_t)i * NWORDS;
    for (int w = wd; w < 157; ++w) {
        float4 bj = sbox4[(w << 6) + lane];     // coalesced dwordx4
        float xx1 = fmaxf(bi.x, bj.x);
        float yy1 = fmaxf(bi.y, bj.y);
        float xx2 = fminf(bi.z, bj.z);
        float yy2 = fminf(bi.w, bj.w);
        float iw = fmaxf(xx2 - xx1, 0.f);
        float ih = fmaxf(yy2 - yy1, 0.f);
        float inter = iw * ih;
        float aj = (bj.z - bj.x) * (bj.w - bj.y);
        float uni = ai + aj - inter;
        u64 b = __ballot(inter > 0.7f * uni);
        if (w == wd)  b &= diagmask;
        if (w == 156) b &= 0xFFFFull;
        if (lane == 0) {
            rowp[w] = b;
            if (w == wd) selfw[i] = b;
        }
    }
}

// ---------------------------------------------------------------------------
// K5 v3: word-batched greedy NMS scan with depth-8 selfw register ring.
// R10 diagnosis: 81us was the per-word serial chain — a selfw global load
// (~500-800 cyc L2/L3) hidden by only ~100 cyc of work, x157 words. The ring
// prefetches 8 words of selfw two groups ahead (static register indexing via
// unrolled inner loop) -> one stall per 8 words.
// ---------------------------------------------------------------------------
__global__ __launch_bounds__(64) void k5_scan(const u64* __restrict__ rows,
                                              const u64* __restrict__ selfw,
                                              const u32* __restrict__ sInv,
                                              const float* __restrict__ sS,
                                              const float* __restrict__ sx1, const float* __restrict__ sy1,
                                              const float* __restrict__ sx2, const float* __restrict__ sy2,
                                              float* __restrict__ out)
{
    __shared__ int keptList[2000];
    __shared__ int kcnt;
    int l = threadIdx.x;
    auto bw = [&](int w) -> u64 {
        const uint4* p = (const uint4*)(sInv + (size_t)w * 64);
        u64 v = 0;
#pragma unroll
        for (int j = 0; j < 16; ++j) {
            uint4 q = p[j];
            v |= ((u64)(q.x != 0) << (j * 4))     | ((u64)(q.y != 0) << (j * 4 + 1))
               | ((u64)(q.z != 0) << (j * 4 + 2)) | ((u64)(q.w != 0) << (j * 4 + 3));
        }
        return v;
    };
    u64 r0 = bw(l);
    u64 r1 = bw(64 + l);
    u64 r2 = (l < 32) ? bw(128 + l) : ~0ull;

    u64 cur[8], nxt[8];
#pragma unroll
    for (int k = 0; k < 8; ++k) cur[k] = selfw[(size_t)k * 64 + l];
#pragma unroll
    for (int k = 0; k < 8; ++k) {
        int ww = 8 + k;
        nxt[k] = (ww < 157) ? selfw[(size_t)ww * 64 + l] : 0ull;
    }

    int cnt = 0;
    bool done = false;
    for (int wg = 0; wg < 20; ++wg) {
#pragma unroll
        for (int ph = 0; ph < 8; ++ph) {
            int w = wg * 8 + ph;
            if (done || w > 156) continue;
            u64 swreg = cur[ph];                 // static index (unrolled)
            int slot = w >> 6, owner = w & 63;
            u64 val = (slot == 0) ? r0 : (slot == 1) ? r1 : r2;
            u64 rw = __shfl(val, owner, 64);
            u64 wmask = (w == 156) ? 0xFFFFull : ~0ull;
            u64 av = (~rw) & wmask;
            u64 km = 0;
            while (av) {                 // intra-word resolve, registers only
                int b = __ffsll((unsigned long long)av) - 1;
                u64 sw = __shfl(swreg, b, 64);
                km |= 1ull << b;
                av &= ~(1ull << b);
                av &= ~sw;
            }
            u64 kk = km;
            while (kk) {                 // OR kept rows, 16 per batch
                int bsx[16];
                int nb = 0;
                while (kk && nb < 16) {
                    int b = __ffsll((unsigned long long)kk) - 1;
                    kk &= kk - 1;
                    bsx[nb++] = b;
                }
                u64 a0 = 0, a1 = 0, a2 = 0;
#pragma unroll
                for (int u = 0; u < 16; ++u) {
                    if (u < nb) {
                        int i = (w << 6) + bsx[u];
                        if (l == 0 && cnt + u < 2000) keptList[cnt + u] = i;
                        const u64* rp = rows + (size_t)i * NWORDS;
                        a0 |= rp[l];
                        a1 |= rp[64 + l];
                        if (l < 32) a2 |= rp[128 + l];
                    }
                }
                r0 |= a0; r1 |= a1; r2 |= a2;
                cnt += nb;
                if (cnt >= 2000) { done = true; break; }
            }
        }
        if (!done) {
            int base = (wg + 2) * 8;
#pragma unroll
            for (int k = 0; k < 8; ++k) cur[k] = nxt[k];
#pragma unroll
            for (int k = 0; k < 8; ++k) {
                int ww = base + k;
                nxt[k] = (ww < 157) ? selfw[(size_t)ww * 64 + l] : 0ull;
            }
        }
    }
    if (l == 0) kcnt = (cnt < 2000) ? cnt : 2000;
    __syncthreads();
    int K = kcnt;
    for (int r = l; r < 2000; r += 64) {
        if (r < K) {
            int j = keptList[r];
            out[r * 4 + 0] = sx1[j];
            out[r * 4 + 1] = sy1[j];
            out[r * 4 + 2] = sx2[j];
            out[r * 4 + 3] = sy2[j];
            out[8000 + r]  = sS[j];
        } else {
            out[r * 4 + 0] = 0.f; out[r * 4 + 1] = 0.f;
            out[r * 4 + 2] = 0.f; out[r * 4 + 3] = 0.f;
            out[8000 + r]  = 0.f;
        }
    }
}

// ---------------------------------------------------------------------------
extern "C" void kernel_launch(void* const* d_in, const int* in_sizes, int n_in,
                              void* d_out, int out_size, void* d_ws, size_t ws_size,
                              hipStream_t stream)
{
    (void)in_sizes; (void)n_in; (void)out_size;
    const float* feat = (const float*)d_in[1];
    const float* wrpn = (const float*)d_in[3];
    const float* brpn = (const float*)d_in[4];
    const float* wcls = (const float*)d_in[5];
    const float* bcls = (const float*)d_in[6];
    const float* wreg = (const float*)d_in[7];
    const float* breg = (const float*)d_in[8];
    float* out = (float*)d_out;

    // K-split factor by workspace budget. need(ns) = ns*512*2560*4 + 16,252,928.
    int ns = (ws_size >= 58195968) ? 8 : (ws_size >= 37224448) ? 4 : 2;
    int cpt     = 8 / ns;                 // 64c-chunks per tap per z-slice
    int cptLog  = (ns == 2) ? 2 : (ns == 4) ? 1 : 0;
    int cptm1   = cpt - 1;
    int cptMul  = cpt * 64;               // c0base = bs * cptMul
    int niter   = 9 * cpt;
    size_t pkB = (size_t)ns * 512 * 2560 * 4;

    char* ws = (char*)d_ws;
    // Live ranges:
    //   [0,pkB)            pk     k1m..k2a
    //   [pkB,pkB+16.25M)   Xt+W   kprep..k1m; then smalls (k2a+), part
    //                      (k2a..k2b) and rows (memset/k4..k5) share offsets.
    float* pk = (float*)ws;
    unsigned short* Xthi = (unsigned short*)(ws + pkB);
    unsigned short* Xtlo = Xthi + (size_t)52 * 64 * 512;
    unsigned short* Whi  = (unsigned short*)(ws + pkB + 6815744);
    unsigned short* Wlo  = Whi + (size_t)512 * 4608;

    char* sm = ws + pkB;
    float* score = (float*)(sm + 0);             // 90,000
    float* bx1   = (float*)(sm + 90000);
    float* by1   = (float*)(sm + 180000);
    float* bx2   = (float*)(sm + 270000);
    float* by2   = (float*)(sm + 360000);
    u32*   valid = (u32*)  (sm + 450000);        // 90,000
    u64*   key   = (u64*)  (sm + 540000);        // 180,000
    u32*   rankp = (u32*)  (sm + 720000);        // 900,000 (10 chunks)
    float* sS    = (float*)(sm + 1620000);       // 40,000
    float* sx1   = (float*)(sm + 1660000);
    float* sy1   = (float*)(sm + 1700000);
    float* sx2   = (float*)(sm + 1740000);
    float* sy2   = (float*)(sm + 1780000);
    u32*   sInv  = (u32*)  (sm + 1820000);       // 40,960
    u64*   selfw = (u64*)  (sm + 1860960);       // 81,920
    float4* sbox4= (float4*)(sm + 1942880);      // 163,840 (10240 entries)
    float* part  = (float*)(sm + 2106720);       // 3,600,000 (k2a..k2b)
    u64*   rows  = (u64*)  (sm + 2106720);       // 12,800,000 (k4..k5) -> ends sm+14.91M < 16.25M
    // peak footprint = pkB + 16,252,928 (ns=4 -> 37.2 MB, proven available)

    AnchorBase ab;
    {
        const float scales[3] = {128.f, 256.f, 512.f};
        const float aspect[3] = {0.5f, 1.f, 2.f};
        for (int ai = 0; ai < 3; ++ai) {
            float hr = sqrtf(aspect[ai]);
            float wratio = 1.0f / hr;
            for (int si = 0; si < 3; ++si) {
                float wsz = wratio * scales[si];
                float hsz = hr * scales[si];
                int a = ai * 3 + si;
                ab.b[a * 4 + 0] = rintf(-wsz / 2.0f);
                ab.b[a * 4 + 1] = rintf(-hsz / 2.0f);
                ab.b[a * 4 + 2] = rintf( wsz / 2.0f);
                ab.b[a * 4 + 3] = rintf( hsz / 2.0f);
            }
        }
    }

    kprep    <<<928, 256, 0, stream>>>(feat, wrpn, Xthi, Xtlo, Whi, Wlo);
    k1m      <<<dim3(4, 40, ns), 256, 0, stream>>>(Xthi, Xtlo, Whi, Wlo, pk,
                                                   cptLog, cptm1, cptMul, niter);
    k2a_heads<<<dim3(40, 8), 256, 0, stream>>>(pk, ns, brpn, wcls, wreg, part);
    k2b_decode<<<88, 256, 0, stream>>>(part, bcls, breg, ab, score, bx1, by1, bx2, by2, valid, key);
    k3a_rank <<<dim3(22, 10), 256, 0, stream>>>(key, rankp);
    k3b_gather<<<88, 256, 0, stream>>>(rankp, score, bx1, by1, bx2, by2, valid,
                                       sS, sx1, sy1, sx2, sy2, sbox4, sInv);
    hipMemsetAsync(rows, 0, (size_t)PRE_TOPK * NWORDS * 8, stream);   // sub-diagonal + tail words
    k4_mat   <<<2500, 256, 0, stream>>>(sbox4, rows, selfw);
    k5_scan  <<<1, 64, 0, stream>>>(rows, selfw, sInv, sS, sx1, sy1, sx2, sy2, out);
}